// Round 1
// baseline (8648.170 us; speedup 1.0000x reference)
//
#include <hip/hip_runtime.h>
#include <cstdint>
#include <cstddef>

typedef unsigned short u16;
typedef __bf16 bf16x8 __attribute__((ext_vector_type(8)));
typedef float f32x4 __attribute__((ext_vector_type(4)));
typedef unsigned short u16x8 __attribute__((ext_vector_type(8)));
typedef unsigned short u16x4 __attribute__((ext_vector_type(4)));

constexpr int cV  = 50257;
constexpr int cT  = 1024;
constexpr int cE  = 1024;
constexpr int cL  = 12;
constexpr int cFF = 4096;
constexpr int cBT = 4096;   // B*T

__device__ __forceinline__ u16 f2bf(float f) {
  union { float f; unsigned u; } x; x.f = f;
  unsigned r = x.u + 0x7fffu + ((x.u >> 16) & 1u);   // RNE
  return (u16)(r >> 16);
}

// ---------------- embedding: x = tok_emb[idx] + pos_emb ----------------
__global__ __launch_bounds__(256) void k_embed(const int* __restrict__ idx,
    const float* __restrict__ tok, const float* __restrict__ pos,
    float* __restrict__ x) {
  const int row = blockIdx.x;            // 0..BT-1
  const int t = row & (cT - 1);
  const int tk = idx[row];
  const float4* tv = (const float4*)(tok + (size_t)tk * cE);
  const float4* pv = (const float4*)(pos + (size_t)t * cE);
  float4* xv = (float4*)(x + (size_t)row * cE);
  const int i = threadIdx.x;             // 256 threads, E/4 float4
  float4 a = tv[i];
  float4 p = pv[i];
  a.x += p.x; a.y += p.y; a.z += p.z; a.w += p.w;
  xv[i] = a;
}

// ---------------- layernorm (f32 in -> bf16 out) ----------------
__global__ __launch_bounds__(256) void k_ln(const float* __restrict__ x,
    const float* __restrict__ gw, const float* __restrict__ bw,
    u16* __restrict__ out) {
  const int row = blockIdx.x;
  const int t = threadIdx.x;
  const float4 v = ((const float4*)(x + (size_t)row * cE))[t];
  float s1 = v.x + v.y + v.z + v.w;
  float s2 = v.x * v.x + v.y * v.y + v.z * v.z + v.w * v.w;
  #pragma unroll
  for (int off = 32; off; off >>= 1) {
    s1 += __shfl_xor(s1, off);
    s2 += __shfl_xor(s2, off);
  }
  __shared__ float red[8];
  const int wid = t >> 6;
  if ((t & 63) == 0) { red[wid] = s1; red[4 + wid] = s2; }
  __syncthreads();
  s1 = red[0] + red[1] + red[2] + red[3];
  s2 = red[4] + red[5] + red[6] + red[7];
  const float mean = s1 * (1.0f / cE);
  const float var = s2 * (1.0f / cE) - mean * mean;
  const float rs = rsqrtf(var + 1e-5f);
  const float4 g4 = ((const float4*)gw)[t];
  const float4 b4 = ((const float4*)bw)[t];
  u16x4 o;
  o[0] = f2bf((v.x - mean) * rs * g4.x + b4.x);
  o[1] = f2bf((v.y - mean) * rs * g4.y + b4.y);
  o[2] = f2bf((v.z - mean) * rs * g4.z + b4.z);
  o[3] = f2bf((v.w - mean) * rs * g4.w + b4.w);
  *(u16x4*)(out + (size_t)row * cE + t * 4) = o;
}

// ---------------- GEMM: C[M,N] = A[M,K](bf16) @ B[K,N](f32->bf16) ----------------
// 128x128 tile, BK=32, 256 threads = 4 waves (2x2), 64x64 per wave (4x4 frags).
// EPI: 0 = bf16 out (no bias, qkv; sel picks B/out of 3)
//      1 = f32 residual: of += acc + bias
//      2 = bf16 gelu(acc + bias)
//      3 = f32 head: acc + bias, ragged-N guarded
template<int EPI>
__global__ __launch_bounds__(256, 2) void k_gemm(
    const u16* __restrict__ A,
    const float* __restrict__ B0, const float* __restrict__ B1,
    const float* __restrict__ B2, const float* __restrict__ bias,
    u16* __restrict__ o0, u16* __restrict__ o1, u16* __restrict__ o2,
    float* __restrict__ of, int M, int N, int K) {
  __shared__ u16 Al[128 * 32];   // [row][k] 64B rows
  __shared__ u16 Bl[32 * 128];   // [k][n] 256B rows
  const int tid = threadIdx.x;
  const int lane = tid & 63;
  const int wid = tid >> 6;
  const int ntile = (N + 127) >> 7;
  const int sel = blockIdx.x / ntile;
  const int bn = blockIdx.x - sel * ntile;
  const int bm = blockIdx.y;
  const float* Bp = (sel == 0) ? B0 : ((sel == 1) ? B1 : B2);
  u16* obf = (sel == 0) ? o0 : ((sel == 1) ? o1 : o2);
  const int wr = wid >> 1, wc = wid & 1;
  const int l15 = lane & 15, lg = lane >> 4;

  f32x4 acc[4][4];
  #pragma unroll
  for (int i = 0; i < 4; ++i) {
    #pragma unroll
    for (int j = 0; j < 4; ++j) {
      f32x4 z = {0.f, 0.f, 0.f, 0.f};
      acc[i][j] = z;
    }
  }

  const u16* Abase = A + (size_t)(bm * 128) * K;
  const int ar0 = tid >> 2;              // rows 0..63
  const int ac0 = (tid & 3) * 8;         // 8-elem (16B) chunk within 32-k row
  const int brow = tid >> 3;             // 0..31
  const int bc0 = (tid & 7) * 16;        // 16 f32 per thread per row

  for (int kt = 0; kt < K; kt += 32) {
    // ---- stage A tile [128][32] bf16 (2 x 16B per thread) ----
    *(u16x8*)(Al + ar0 * 32 + ac0) =
        *(const u16x8*)(Abase + (size_t)ar0 * K + kt + ac0);
    *(u16x8*)(Al + (ar0 + 64) * 32 + ac0) =
        *(const u16x8*)(Abase + (size_t)(ar0 + 64) * K + kt + ac0);
    // ---- stage B tile [32][128]: f32 load, cvt, bf16 store ----
    {
      const float* bsrc = Bp + (size_t)(kt + brow) * N + bn * 128 + bc0;
      alignas(16) u16 tmp[16];
      if (EPI == 3) {            // ragged / odd-N: guarded scalar loads
        const int colbase = bn * 128 + bc0;
        #pragma unroll
        for (int q = 0; q < 16; ++q)
          tmp[q] = f2bf((colbase + q < N) ? bsrc[q] : 0.0f);
      } else {
        #pragma unroll
        for (int q = 0; q < 4; ++q) {
          const float4 f = *(const float4*)(bsrc + q * 4);
          tmp[q * 4 + 0] = f2bf(f.x); tmp[q * 4 + 1] = f2bf(f.y);
          tmp[q * 4 + 2] = f2bf(f.z); tmp[q * 4 + 3] = f2bf(f.w);
        }
      }
      *(u16x8*)(Bl + brow * 128 + bc0) = *(const u16x8*)tmp;
      *(u16x8*)(Bl + brow * 128 + bc0 + 8) = *(const u16x8*)(tmp + 8);
    }
    __syncthreads();

    bf16x8 af[4];
    #pragma unroll
    for (int mi = 0; mi < 4; ++mi)
      af[mi] = *(const bf16x8*)(Al + (wr * 64 + mi * 16 + l15) * 32 + lg * 8);
    #pragma unroll
    for (int ni = 0; ni < 4; ++ni) {
      u16x8 tv;
      #pragma unroll
      for (int i = 0; i < 8; ++i)
        tv[i] = Bl[(lg * 8 + i) * 128 + wc * 64 + ni * 16 + l15];
      const bf16x8 bfr = __builtin_bit_cast(bf16x8, tv);
      #pragma unroll
      for (int mi = 0; mi < 4; ++mi)
        acc[mi][ni] = __builtin_amdgcn_mfma_f32_16x16x32_bf16(af[mi], bfr, acc[mi][ni], 0, 0, 0);
    }
    __syncthreads();
  }

  // ---- epilogue: D row = (lane>>4)*4 + r, col = lane&15 (m89-verified) ----
  #pragma unroll
  for (int mi = 0; mi < 4; ++mi) {
    const int grow = bm * 128 + wr * 64 + mi * 16 + lg * 4;
    #pragma unroll
    for (int ni = 0; ni < 4; ++ni) {
      const int gcol = bn * 128 + wc * 64 + ni * 16 + l15;
      #pragma unroll
      for (int r = 0; r < 4; ++r) {
        const float a = acc[mi][ni][r];
        const size_t oidx = (size_t)(grow + r) * N + gcol;
        if (EPI == 0) {
          obf[oidx] = f2bf(a);
        } else if (EPI == 1) {
          of[oidx] += a + bias[gcol];
        } else if (EPI == 2) {
          const float gv = a + bias[gcol];
          obf[oidx] = f2bf(0.5f * gv * (1.0f + erff(gv * 0.70710678118f)));
        } else {
          if (gcol < N) of[oidx] = a + bias[gcol];
        }
      }
    }
  }
}

// ---------------- causal flash attention ----------------
// grid (T/64, B*H); block 256 = 4 waves; wave w owns 16 q-rows.
__global__ __launch_bounds__(256, 2) void k_attn(
    const u16* __restrict__ qg, const u16* __restrict__ kg,
    const u16* __restrict__ vg, u16* __restrict__ og) {
  __shared__ u16 Kl[64 * 64];        // [k-row][d]
  __shared__ u16 Vt[64 * 64];        // [d][k-row] (transposed at stage)
  __shared__ u16 Pl[4][16 * 64];     // per-wave P relayout buffer
  const int tid = threadIdx.x;
  const int lane = tid & 63;
  const int w = tid >> 6;
  const int qt = blockIdx.x;         // 0..15
  const int bh = blockIdx.y;         // 0..63
  const int b = bh >> 4, h = bh & 15;
  const int l15 = lane & 15, lg = lane >> 4;

  const size_t qrow0 = (size_t)b * cT + qt * 64 + w * 16;
  bf16x8 aq[2];
  #pragma unroll
  for (int c = 0; c < 2; ++c)
    aq[c] = *(const bf16x8*)(qg + (qrow0 + l15) * cE + h * 64 + c * 32 + lg * 8);

  f32x4 acco[4];
  #pragma unroll
  for (int j = 0; j < 4; ++j) { f32x4 z = {0.f,0.f,0.f,0.f}; acco[j] = z; }
  float mrun[4], lrun[4];
  #pragma unroll
  for (int r = 0; r < 4; ++r) { mrun[r] = -1e30f; lrun[r] = 0.f; }

  for (int kt = 0; kt <= qt; ++kt) {
    const size_t krow0 = (size_t)b * cT + kt * 64;
    #pragma unroll
    for (int u = 0; u < 2; ++u) {
      const int un = tid + u * 256;          // 512 units of 8 bf16
      const int rr = un >> 3, c8 = (un & 7) * 8;
      *(u16x8*)(Kl + rr * 64 + c8) =
          *(const u16x8*)(kg + (krow0 + rr) * cE + h * 64 + c8);
      const u16x8 vv = *(const u16x8*)(vg + (krow0 + rr) * cE + h * 64 + c8);
      #pragma unroll
      for (int i = 0; i < 8; ++i)
        Vt[(c8 + i) * 64 + rr] = vv[i];
    }
    __syncthreads();

    // S = Q K^T  (16 q-rows x 64 k-cols per wave)
    f32x4 s[4];
    #pragma unroll
    for (int j = 0; j < 4; ++j) { f32x4 z = {0.f,0.f,0.f,0.f}; s[j] = z; }
    #pragma unroll
    for (int c = 0; c < 2; ++c) {
      #pragma unroll
      for (int j = 0; j < 4; ++j) {
        const bf16x8 kb2 = *(const bf16x8*)(Kl + (j * 16 + l15) * 64 + c * 32 + lg * 8);
        s[j] = __builtin_amdgcn_mfma_f32_16x16x32_bf16(aq[c], kb2, s[j], 0, 0, 0);
      }
    }

    float sv[4][4];
    const bool diag = (kt == qt);
    #pragma unroll
    for (int j = 0; j < 4; ++j) {
      #pragma unroll
      for (int r = 0; r < 4; ++r) {
        float xs = s[j][r] * 0.125f;             // HD^-0.5
        if (diag && (j * 16 + l15) > (w * 16 + lg * 4 + r)) xs = -1e30f;
        sv[j][r] = xs;
      }
    }

    // online softmax; row stats shared across the 16-lane group
    float corr[4];
    #pragma unroll
    for (int r = 0; r < 4; ++r) {
      float mx = fmaxf(fmaxf(sv[0][r], sv[1][r]), fmaxf(sv[2][r], sv[3][r]));
      #pragma unroll
      for (int off = 1; off < 16; off <<= 1) mx = fmaxf(mx, __shfl_xor(mx, off));
      const float mnew = fmaxf(mrun[r], mx);
      corr[r] = __expf(mrun[r] - mnew);
      float rs = 0.f;
      #pragma unroll
      for (int j = 0; j < 4; ++j) {
        const float p = __expf(sv[j][r] - mnew);
        sv[j][r] = p;
        rs += p;
      }
      #pragma unroll
      for (int off = 1; off < 16; off <<= 1) rs += __shfl_xor(rs, off);
      lrun[r] = lrun[r] * corr[r] + rs;
      mrun[r] = mnew;
    }

    // P -> LDS (relayout to A-fragment order), rescale O
    #pragma unroll
    for (int j = 0; j < 4; ++j) {
      #pragma unroll
      for (int r = 0; r < 4; ++r) {
        Pl[w][(lg * 4 + r) * 64 + j * 16 + l15] = f2bf(sv[j][r]);
        acco[j][r] *= corr[r];
      }
    }

    // O += P @ V
    #pragma unroll
    for (int c = 0; c < 2; ++c) {
      const bf16x8 pa = *(const bf16x8*)(Pl[w] + l15 * 64 + c * 32 + lg * 8);
      #pragma unroll
      for (int j = 0; j < 4; ++j) {
        const bf16x8 vb2 = *(const bf16x8*)(Vt + (j * 16 + l15) * 64 + c * 32 + lg * 8);
        acco[j] = __builtin_amdgcn_mfma_f32_16x16x32_bf16(pa, vb2, acco[j], 0, 0, 0);
      }
    }
    __syncthreads();
  }

  #pragma unroll
  for (int j = 0; j < 4; ++j) {
    #pragma unroll
    for (int r = 0; r < 4; ++r)
      og[(qrow0 + lg * 4 + r) * cE + h * 64 + j * 16 + l15] = f2bf(acco[j][r] / lrun[r]);
  }
}

// ---------------- per-row NLL over V ----------------
__global__ __launch_bounds__(256) void k_nll(const float* __restrict__ logits,
    const int* __restrict__ tgt, float* __restrict__ nll) {
  const int row = blockIdx.x;
  const float* lp = logits + (size_t)row * cV;
  const int t = threadIdx.x;
  __shared__ float red[8];
  const int wid = t >> 6, lane = t & 63;
  float mx = -1e30f;
  for (int i = t; i < cV; i += 256) mx = fmaxf(mx, lp[i]);
  #pragma unroll
  for (int off = 32; off; off >>= 1) mx = fmaxf(mx, __shfl_xor(mx, off));
  if (lane == 0) red[wid] = mx;
  __syncthreads();
  mx = fmaxf(fmaxf(red[0], red[1]), fmaxf(red[2], red[3]));
  float s = 0.f;
  for (int i = t; i < cV; i += 256) s += __expf(lp[i] - mx);
  #pragma unroll
  for (int off = 32; off; off >>= 1) s += __shfl_xor(s, off);
  if (lane == 0) red[4 + wid] = s;
  __syncthreads();
  if (t == 0) {
    s = red[4] + red[5] + red[6] + red[7];
    nll[row] = logf(s) + mx - lp[tgt[row]];
  }
}

__global__ __launch_bounds__(256) void k_loss(const float* __restrict__ nll,
    float* __restrict__ out) {
  const int t = threadIdx.x;
  float s = 0.f;
  for (int i = t; i < cBT; i += 256) s += nll[i];
  #pragma unroll
  for (int off = 32; off; off >>= 1) s += __shfl_xor(s, off);
  __shared__ float red[4];
  if ((t & 63) == 0) red[t >> 6] = s;
  __syncthreads();
  if (t == 0) out[0] = (red[0] + red[1] + red[2] + red[3]) * (1.0f / cBT);
}

extern "C" void kernel_launch(void* const* d_in, const int* in_sizes, int n_in,
                              void* d_out, int out_size, void* d_ws, size_t ws_size,
                              hipStream_t stream) {
  const int*   idx  = (const int*)d_in[0];
  const int*   tgt  = (const int*)d_in[1];
  const float* tok  = (const float*)d_in[2];
  const float* pos  = (const float*)d_in[3];
  const float* Wq   = (const float*)d_in[4];
  const float* Wk   = (const float*)d_in[5];
  const float* Wv   = (const float*)d_in[6];
  const float* Wo   = (const float*)d_in[7];
  const float* bo   = (const float*)d_in[8];
  const float* ln1g = (const float*)d_in[9];
  const float* ln1b = (const float*)d_in[10];
  const float* ln2g = (const float*)d_in[11];
  const float* ln2b = (const float*)d_in[12];
  const float* W1   = (const float*)d_in[13];
  const float* b1   = (const float*)d_in[14];
  const float* W2   = (const float*)d_in[15];
  const float* b2   = (const float*)d_in[16];
  const float* lnfg = (const float*)d_in[17];
  const float* lnfb = (const float*)d_in[18];
  const float* Wh   = (const float*)d_in[19];
  const float* bh   = (const float*)d_in[20];

  // Scratch plan: activations live in the front of d_out (dead before the
  // head GEMM overwrites all of d_out with logits). Only lnf output + nll
  // need d_ws (~8.4 MB).
  char* ob = (char*)d_out;
  float* x    = (float*)ob;                  // [BT,E] f32   (16 MB)
  u16* hb     = (u16*)(ob + 16777216);       // [BT,E] bf16  ( 8 MB)
  u16* qb     = (u16*)(ob + 25165824);       // [BT,E] bf16
  u16* kb     = (u16*)(ob + 33554432);
  u16* vb     = (u16*)(ob + 41943040);
  u16* abuf   = (u16*)(ob + 50331648);       // attn out bf16
  u16* fbuf   = (u16*)(ob + 58720256);       // [BT,FF] bf16 (32 MB, ends 92.3 MB)
  u16* hf     = (u16*)d_ws;                  // lnf out bf16 (8.4 MB)
  float* nll  = (float*)((char*)d_ws + 8388608);
  float* logits = (float*)d_out;
  float* loss = logits + (size_t)cBT * cV;

  const dim3 blk(256);
  k_embed<<<dim3(cBT), blk, 0, stream>>>(idx, tok, pos, x);
  for (int l = 0; l < cL; ++l) {
    const size_t wo2 = (size_t)l * cE * cE;
    k_ln<<<dim3(cBT), blk, 0, stream>>>(x, ln1g + l * cE, ln1b + l * cE, hb);
    k_gemm<0><<<dim3(24, 32), blk, 0, stream>>>(hb, Wq + wo2, Wk + wo2, Wv + wo2,
        nullptr, qb, kb, vb, nullptr, cBT, cE, cE);
    k_attn<<<dim3(16, 64), blk, 0, stream>>>(qb, kb, vb, abuf);
    k_gemm<1><<<dim3(8, 32), blk, 0, stream>>>(abuf, Wo + wo2, nullptr, nullptr,
        bo + l * cE, nullptr, nullptr, nullptr, x, cBT, cE, cE);
    k_ln<<<dim3(cBT), blk, 0, stream>>>(x, ln2g + l * cE, ln2b + l * cE, hb);
    k_gemm<2><<<dim3(32, 32), blk, 0, stream>>>(hb, W1 + (size_t)l * cE * cFF, nullptr, nullptr,
        b1 + l * cFF, fbuf, nullptr, nullptr, nullptr, cBT, cFF, cE);
    k_gemm<1><<<dim3(8, 32), blk, 0, stream>>>(fbuf, W2 + (size_t)l * cFF * cE, nullptr, nullptr,
        b2 + l * cE, nullptr, nullptr, nullptr, x, cBT, cE, cFF);
  }
  k_ln<<<dim3(cBT), blk, 0, stream>>>(x, lnfg, lnfb, hf);
  k_gemm<3><<<dim3(393, 32), blk, 0, stream>>>(hf, Wh, nullptr, nullptr, bh,
      nullptr, nullptr, nullptr, logits, cBT, cV, cE);
  k_nll<<<dim3(cBT), blk, 0, stream>>>(logits, tgt, nll);
  k_loss<<<dim3(1), blk, 0, stream>>>(nll, loss);
}

// Round 2
// 5995.503 us; speedup vs baseline: 1.4424x; 1.4424x over previous
//
#include <hip/hip_runtime.h>
#include <cstdint>
#include <cstddef>

typedef unsigned short u16;
typedef __bf16 bf16x8 __attribute__((ext_vector_type(8)));
typedef float f32x4 __attribute__((ext_vector_type(4)));
typedef unsigned short u16x8 __attribute__((ext_vector_type(8)));
typedef unsigned short u16x4 __attribute__((ext_vector_type(4)));

constexpr int cV  = 50257;
constexpr int cVp = 50304;   // padded to 128
constexpr int cT  = 1024;
constexpr int cE  = 1024;
constexpr int cL  = 12;
constexpr int cFF = 4096;
constexpr int cBT = 4096;    // B*T

__device__ __forceinline__ u16 f2bf(float f) {
  union { float f; unsigned u; } x; x.f = f;
  unsigned r = x.u + 0x7fffu + ((x.u >> 16) & 1u);   // RNE
  return (u16)(r >> 16);
}

// async global->LDS, 16B per lane. dest must be linear in lane order.
__device__ __forceinline__ void gload16(const void* g, void* l) {
  __builtin_amdgcn_global_load_lds(
      (const __attribute__((address_space(1))) void*)g,
      (__attribute__((address_space(3))) void*)l, 16, 0, 0);
}

// ---------------- embedding ----------------
__global__ __launch_bounds__(256) void k_embed(const int* __restrict__ idx,
    const float* __restrict__ tok, const float* __restrict__ pos,
    float* __restrict__ x) {
  const int row = blockIdx.x;
  const int t = row & (cT - 1);
  const int tk = idx[row];
  const float4* tv = (const float4*)(tok + (size_t)tk * cE);
  const float4* pv = (const float4*)(pos + (size_t)t * cE);
  float4* xv = (float4*)(x + (size_t)row * cE);
  const int i = threadIdx.x;
  float4 a = tv[i];
  float4 p = pv[i];
  a.x += p.x; a.y += p.y; a.z += p.z; a.w += p.w;
  xv[i] = a;
}

// ---------------- layernorm (f32 in -> bf16 out) ----------------
__global__ __launch_bounds__(256) void k_ln(const float* __restrict__ x,
    const float* __restrict__ gw, const float* __restrict__ bw,
    u16* __restrict__ out) {
  const int row = blockIdx.x;
  const int t = threadIdx.x;
  const float4 v = ((const float4*)(x + (size_t)row * cE))[t];
  float s1 = v.x + v.y + v.z + v.w;
  float s2 = v.x * v.x + v.y * v.y + v.z * v.z + v.w * v.w;
  #pragma unroll
  for (int off = 32; off; off >>= 1) {
    s1 += __shfl_xor(s1, off);
    s2 += __shfl_xor(s2, off);
  }
  __shared__ float red[8];
  const int wid = t >> 6;
  if ((t & 63) == 0) { red[wid] = s1; red[4 + wid] = s2; }
  __syncthreads();
  s1 = red[0] + red[1] + red[2] + red[3];
  s2 = red[4] + red[5] + red[6] + red[7];
  const float mean = s1 * (1.0f / cE);
  const float var = s2 * (1.0f / cE) - mean * mean;
  const float rs = rsqrtf(var + 1e-5f);
  const float4 g4 = ((const float4*)gw)[t];
  const float4 b4 = ((const float4*)bw)[t];
  u16x4 o;
  o[0] = f2bf((v.x - mean) * rs * g4.x + b4.x);
  o[1] = f2bf((v.y - mean) * rs * g4.y + b4.y);
  o[2] = f2bf((v.z - mean) * rs * g4.z + b4.z);
  o[3] = f2bf((v.w - mean) * rs * g4.w + b4.w);
  *(u16x4*)(out + (size_t)row * cE + t * 4) = o;
}

// ---------------- weight convert+transpose: f32[K][N] -> bf16[N][K] ----------------
// grid (Nrows/32, K/32, L); pads rows [Nsrc,Nrows) with 0.
__global__ __launch_bounds__(256) void k_cvt_t(const float* __restrict__ src,
    u16* __restrict__ dst, int K, int Nsrc, size_t sstride, size_t dstride) {
  __shared__ float tile[32][33];
  const float* s = src + blockIdx.z * sstride;
  u16* d = dst + blockIdx.z * dstride;
  const int n0 = blockIdx.x * 32, k0 = blockIdx.y * 32;
  const int t = threadIdx.x;
  const int c = t & 31, r0 = t >> 5;          // c: 0..31, r0: 0..7
  #pragma unroll
  for (int i = 0; i < 4; ++i) {
    const int kl = r0 + i * 8;
    const int n = n0 + c;
    tile[kl][c] = (n < Nsrc) ? s[(size_t)(k0 + kl) * Nsrc + n] : 0.0f;
  }
  __syncthreads();
  #pragma unroll
  for (int i = 0; i < 4; ++i) {
    const int nl = r0 + i * 8;
    d[(size_t)(n0 + nl) * K + k0 + c] = f2bf(tile[c][nl]);
  }
}

// ---------------- GEMM: C[M,Nout] = A[M][K](bf16) @ Bt[N][K](bf16)^T ----------------
// m97 structure: 128x128 tile, BK=32, global_load_lds w16, ds_read_b128 frags.
// grid (m-tiles, ntile*nsel): consecutive x-blocks share the B panel (L2 reuse).
// EPI: 0 bf16 out (QKV, sel in y) | 1 f32 residual += | 2 bf16 gelu | 3 f32 head (ragged)
template<int EPI>
__global__ __launch_bounds__(256) void k_gemm(
    const u16* __restrict__ A,
    const u16* __restrict__ Bt0, const u16* __restrict__ Bt1,
    const u16* __restrict__ Bt2, const float* __restrict__ bias,
    u16* __restrict__ o0, u16* __restrict__ o1, u16* __restrict__ o2,
    float* __restrict__ of, int K, int Nout, int ntile) {
  __shared__ u16 Al[128 * 32];
  __shared__ u16 Bl[128 * 32];
  const int tid = threadIdx.x;
  const int lane = tid & 63;
  const int wid = tid >> 6;
  const int bm = blockIdx.x;
  const int sel = (int)blockIdx.y / ntile;
  const int bn = (int)blockIdx.y - sel * ntile;
  const u16* Bt = (sel == 0) ? Bt0 : ((sel == 1) ? Bt1 : Bt2);
  u16* obf = (sel == 0) ? o0 : ((sel == 1) ? o1 : o2);
  const int wr = wid >> 1, wc = wid & 1;
  const int l15 = lane & 15, lg = lane >> 4;

  f32x4 acc[4][4];
  #pragma unroll
  for (int i = 0; i < 4; ++i)
    #pragma unroll
    for (int j = 0; j < 4; ++j) { f32x4 z = {0.f,0.f,0.f,0.f}; acc[i][j] = z; }

  const u16* Ab = A + (size_t)(bm * 128) * K;
  const u16* Bb = Bt + (size_t)(bn * 128) * K;
  const int srow = tid >> 2;              // 0..63
  const int scol = (tid & 3) * 8;         // 16B chunk in 32-k row
  char* AlB = (char*)Al;
  char* BlB = (char*)Bl;

  for (int kt = 0; kt < K; kt += 32) {
    gload16(Ab + (size_t)srow * K + kt + scol,        AlB + tid * 16);
    gload16(Ab + (size_t)(srow + 64) * K + kt + scol, AlB + 4096 + tid * 16);
    gload16(Bb + (size_t)srow * K + kt + scol,        BlB + tid * 16);
    gload16(Bb + (size_t)(srow + 64) * K + kt + scol, BlB + 4096 + tid * 16);
    __syncthreads();

    bf16x8 af[4], bf[4];
    #pragma unroll
    for (int mi = 0; mi < 4; ++mi)
      af[mi] = *(const bf16x8*)(Al + (wr * 64 + mi * 16 + l15) * 32 + lg * 8);
    #pragma unroll
    for (int ni = 0; ni < 4; ++ni)
      bf[ni] = *(const bf16x8*)(Bl + (wc * 64 + ni * 16 + l15) * 32 + lg * 8);
    #pragma unroll
    for (int ni = 0; ni < 4; ++ni)
      #pragma unroll
      for (int mi = 0; mi < 4; ++mi)
        acc[mi][ni] = __builtin_amdgcn_mfma_f32_16x16x32_bf16(af[mi], bf[ni], acc[mi][ni], 0, 0, 0);
    __syncthreads();
  }

  #pragma unroll
  for (int mi = 0; mi < 4; ++mi) {
    const int grow = bm * 128 + wr * 64 + mi * 16 + lg * 4;
    #pragma unroll
    for (int ni = 0; ni < 4; ++ni) {
      const int gcol = bn * 128 + wc * 64 + ni * 16 + l15;
      #pragma unroll
      for (int r = 0; r < 4; ++r) {
        const float a = acc[mi][ni][r];
        const size_t oidx = (size_t)(grow + r) * Nout + gcol;
        if (EPI == 0) {
          obf[oidx] = f2bf(a);
        } else if (EPI == 1) {
          of[oidx] += a + bias[gcol];
        } else if (EPI == 2) {
          const float gv = a + bias[gcol];
          obf[oidx] = f2bf(0.5f * gv * (1.0f + erff(gv * 0.70710678118f)));
        } else {
          if (gcol < Nout) of[oidx] = a + bias[gcol];
        }
      }
    }
  }
}

// ---------------- legacy head GEMM (f32 B, used only if d_ws too small) ----------------
__global__ __launch_bounds__(256) void k_gemm_legacy3(
    const u16* __restrict__ A, const float* __restrict__ B0,
    const float* __restrict__ bias, float* __restrict__ of,
    int M, int N, int K) {
  __shared__ u16 Al[128 * 32];
  __shared__ u16 Bl[32 * 128];
  const int tid = threadIdx.x;
  const int lane = tid & 63;
  const int wid = tid >> 6;
  const int bn = blockIdx.x;
  const int bm = blockIdx.y;
  const int wr = wid >> 1, wc = wid & 1;
  const int l15 = lane & 15, lg = lane >> 4;
  f32x4 acc[4][4];
  #pragma unroll
  for (int i = 0; i < 4; ++i)
    #pragma unroll
    for (int j = 0; j < 4; ++j) { f32x4 z = {0.f,0.f,0.f,0.f}; acc[i][j] = z; }
  const u16* Abase = A + (size_t)(bm * 128) * K;
  const int ar0 = tid >> 2;
  const int ac0 = (tid & 3) * 8;
  const int brow = tid >> 3;
  const int bc0 = (tid & 7) * 16;
  for (int kt = 0; kt < K; kt += 32) {
    *(u16x8*)(Al + ar0 * 32 + ac0) =
        *(const u16x8*)(Abase + (size_t)ar0 * K + kt + ac0);
    *(u16x8*)(Al + (ar0 + 64) * 32 + ac0) =
        *(const u16x8*)(Abase + (size_t)(ar0 + 64) * K + kt + ac0);
    {
      const float* bsrc = B0 + (size_t)(kt + brow) * N + bn * 128 + bc0;
      alignas(16) u16 tmp[16];
      const int colbase = bn * 128 + bc0;
      #pragma unroll
      for (int q = 0; q < 16; ++q)
        tmp[q] = f2bf((colbase + q < N) ? bsrc[q] : 0.0f);
      *(u16x8*)(Bl + brow * 128 + bc0) = *(const u16x8*)tmp;
      *(u16x8*)(Bl + brow * 128 + bc0 + 8) = *(const u16x8*)(tmp + 8);
    }
    __syncthreads();
    bf16x8 af[4];
    #pragma unroll
    for (int mi = 0; mi < 4; ++mi)
      af[mi] = *(const bf16x8*)(Al + (wr * 64 + mi * 16 + l15) * 32 + lg * 8);
    #pragma unroll
    for (int ni = 0; ni < 4; ++ni) {
      u16x8 tv;
      #pragma unroll
      for (int i = 0; i < 8; ++i)
        tv[i] = Bl[(lg * 8 + i) * 128 + wc * 64 + ni * 16 + l15];
      const bf16x8 bfr = __builtin_bit_cast(bf16x8, tv);
      #pragma unroll
      for (int mi = 0; mi < 4; ++mi)
        acc[mi][ni] = __builtin_amdgcn_mfma_f32_16x16x32_bf16(af[mi], bfr, acc[mi][ni], 0, 0, 0);
    }
    __syncthreads();
  }
  #pragma unroll
  for (int mi = 0; mi < 4; ++mi) {
    const int grow = bm * 128 + wr * 64 + mi * 16 + lg * 4;
    #pragma unroll
    for (int ni = 0; ni < 4; ++ni) {
      const int gcol = bn * 128 + wc * 64 + ni * 16 + l15;
      #pragma unroll
      for (int r = 0; r < 4; ++r)
        if (gcol < N) of[(size_t)(grow + r) * N + gcol] = acc[mi][ni][r] + bias[gcol];
    }
  }
}

// ---------------- causal flash attention ----------------
__global__ __launch_bounds__(256, 2) void k_attn(
    const u16* __restrict__ qg, const u16* __restrict__ kg,
    const u16* __restrict__ vg, u16* __restrict__ og) {
  __shared__ u16 Kl[64 * 64];
  __shared__ u16 Vt[64 * 64];
  __shared__ u16 Pl[4][16 * 64];
  const int tid = threadIdx.x;
  const int lane = tid & 63;
  const int w = tid >> 6;
  const int qt = blockIdx.x;
  const int bh = blockIdx.y;
  const int b = bh >> 4, h = bh & 15;
  const int l15 = lane & 15, lg = lane >> 4;

  const size_t qrow0 = (size_t)b * cT + qt * 64 + w * 16;
  bf16x8 aq[2];
  #pragma unroll
  for (int c = 0; c < 2; ++c)
    aq[c] = *(const bf16x8*)(qg + (qrow0 + l15) * cE + h * 64 + c * 32 + lg * 8);

  f32x4 acco[4];
  #pragma unroll
  for (int j = 0; j < 4; ++j) { f32x4 z = {0.f,0.f,0.f,0.f}; acco[j] = z; }
  float mrun[4], lrun[4];
  #pragma unroll
  for (int r = 0; r < 4; ++r) { mrun[r] = -1e30f; lrun[r] = 0.f; }

  for (int kt = 0; kt <= qt; ++kt) {
    const size_t krow0 = (size_t)b * cT + kt * 64;
    #pragma unroll
    for (int u = 0; u < 2; ++u) {
      const int un = tid + u * 256;
      const int rr = un >> 3, c8 = (un & 7) * 8;
      *(u16x8*)(Kl + rr * 64 + c8) =
          *(const u16x8*)(kg + (krow0 + rr) * cE + h * 64 + c8);
      const u16x8 vv = *(const u16x8*)(vg + (krow0 + rr) * cE + h * 64 + c8);
      #pragma unroll
      for (int i = 0; i < 8; ++i)
        Vt[(c8 + i) * 64 + rr] = vv[i];
    }
    __syncthreads();

    f32x4 s[4];
    #pragma unroll
    for (int j = 0; j < 4; ++j) { f32x4 z = {0.f,0.f,0.f,0.f}; s[j] = z; }
    #pragma unroll
    for (int c = 0; c < 2; ++c) {
      #pragma unroll
      for (int j = 0; j < 4; ++j) {
        const bf16x8 kb2 = *(const bf16x8*)(Kl + (j * 16 + l15) * 64 + c * 32 + lg * 8);
        s[j] = __builtin_amdgcn_mfma_f32_16x16x32_bf16(aq[c], kb2, s[j], 0, 0, 0);
      }
    }

    float sv[4][4];
    const bool diag = (kt == qt);
    #pragma unroll
    for (int j = 0; j < 4; ++j)
      #pragma unroll
      for (int r = 0; r < 4; ++r) {
        float xs = s[j][r] * 0.125f;
        if (diag && (j * 16 + l15) > (w * 16 + lg * 4 + r)) xs = -1e30f;
        sv[j][r] = xs;
      }

    float corr[4];
    #pragma unroll
    for (int r = 0; r < 4; ++r) {
      float mx = fmaxf(fmaxf(sv[0][r], sv[1][r]), fmaxf(sv[2][r], sv[3][r]));
      #pragma unroll
      for (int off = 1; off < 16; off <<= 1) mx = fmaxf(mx, __shfl_xor(mx, off));
      const float mnew = fmaxf(mrun[r], mx);
      corr[r] = __expf(mrun[r] - mnew);
      float rs = 0.f;
      #pragma unroll
      for (int j = 0; j < 4; ++j) {
        const float p = __expf(sv[j][r] - mnew);
        sv[j][r] = p;
        rs += p;
      }
      #pragma unroll
      for (int off = 1; off < 16; off <<= 1) rs += __shfl_xor(rs, off);
      lrun[r] = lrun[r] * corr[r] + rs;
      mrun[r] = mnew;
    }

    #pragma unroll
    for (int j = 0; j < 4; ++j)
      #pragma unroll
      for (int r = 0; r < 4; ++r) {
        Pl[w][(lg * 4 + r) * 64 + j * 16 + l15] = f2bf(sv[j][r]);
        acco[j][r] *= corr[r];
      }

    #pragma unroll
    for (int c = 0; c < 2; ++c) {
      const bf16x8 pa = *(const bf16x8*)(Pl[w] + l15 * 64 + c * 32 + lg * 8);
      #pragma unroll
      for (int j = 0; j < 4; ++j) {
        const bf16x8 vb2 = *(const bf16x8*)(Vt + (j * 16 + l15) * 64 + c * 32 + lg * 8);
        acco[j] = __builtin_amdgcn_mfma_f32_16x16x32_bf16(pa, vb2, acco[j], 0, 0, 0);
      }
    }
    __syncthreads();
  }

  #pragma unroll
  for (int j = 0; j < 4; ++j)
    #pragma unroll
    for (int r = 0; r < 4; ++r)
      og[(qrow0 + lg * 4 + r) * cE + h * 64 + j * 16 + l15] = f2bf(acco[j][r] / lrun[r]);
}

// ---------------- per-row NLL over V ----------------
__global__ __launch_bounds__(256) void k_nll(const float* __restrict__ logits,
    const int* __restrict__ tgt, float* __restrict__ nll) {
  const int row = blockIdx.x;
  const float* lp = logits + (size_t)row * cV;
  const int t = threadIdx.x;
  __shared__ float red[8];
  const int wid = t >> 6, lane = t & 63;
  float mx = -1e30f;
  for (int i = t; i < cV; i += 256) mx = fmaxf(mx, lp[i]);
  #pragma unroll
  for (int off = 32; off; off >>= 1) mx = fmaxf(mx, __shfl_xor(mx, off));
  if (lane == 0) red[wid] = mx;
  __syncthreads();
  mx = fmaxf(fmaxf(red[0], red[1]), fmaxf(red[2], red[3]));
  float s = 0.f;
  for (int i = t; i < cV; i += 256) s += __expf(lp[i] - mx);
  #pragma unroll
  for (int off = 32; off; off >>= 1) s += __shfl_xor(s, off);
  if (lane == 0) red[4 + wid] = s;
  __syncthreads();
  if (t == 0) {
    s = red[4] + red[5] + red[6] + red[7];
    nll[row] = logf(s) + mx - lp[tgt[row]];
  }
}

__global__ __launch_bounds__(256) void k_loss(const float* __restrict__ nll,
    float* __restrict__ out) {
  const int t = threadIdx.x;
  float s = 0.f;
  for (int i = t; i < cBT; i += 256) s += nll[i];
  #pragma unroll
  for (int off = 32; off; off >>= 1) s += __shfl_xor(s, off);
  __shared__ float red[4];
  if ((t & 63) == 0) red[t >> 6] = s;
  __syncthreads();
  if (t == 0) out[0] = (red[0] + red[1] + red[2] + red[3]) * (1.0f / cBT);
}

extern "C" void kernel_launch(void* const* d_in, const int* in_sizes, int n_in,
                              void* d_out, int out_size, void* d_ws, size_t ws_size,
                              hipStream_t stream) {
  const int*   idx  = (const int*)d_in[0];
  const int*   tgt  = (const int*)d_in[1];
  const float* tok  = (const float*)d_in[2];
  const float* pos  = (const float*)d_in[3];
  const float* Wq   = (const float*)d_in[4];
  const float* Wk   = (const float*)d_in[5];
  const float* Wv   = (const float*)d_in[6];
  const float* Wo   = (const float*)d_in[7];
  const float* bo   = (const float*)d_in[8];
  const float* ln1g = (const float*)d_in[9];
  const float* ln1b = (const float*)d_in[10];
  const float* ln2g = (const float*)d_in[11];
  const float* ln2b = (const float*)d_in[12];
  const float* W1   = (const float*)d_in[13];
  const float* b1   = (const float*)d_in[14];
  const float* W2   = (const float*)d_in[15];
  const float* b2   = (const float*)d_in[16];
  const float* lnfg = (const float*)d_in[17];
  const float* lnfb = (const float*)d_in[18];
  const float* Wh   = (const float*)d_in[19];
  const float* bh   = (const float*)d_in[20];

  // --- d_out scratch plan (all dead before head GEMM overwrites d_out) ---
  char* ob = (char*)d_out;
  float* x    = (float*)ob;                          // [BT,E] f32, 16 MB
  u16* hb     = (u16*)(ob + (16u << 20));            // [BT,E] bf16
  u16* qb     = (u16*)(ob + (24u << 20));
  u16* kb     = (u16*)(ob + (32u << 20));
  u16* vb     = (u16*)(ob + (40u << 20));
  u16* abuf   = (u16*)(ob + (48u << 20));
  u16* fbuf   = (u16*)(ob + (56u << 20));            // [BT,FF] bf16, 32 MB -> ends 88M
  // bf16 transposed layer weights (dead before head GEMM):
  u16* WqT    = (u16*)(ob + (128u << 20));           // 12 x [E][E]  (24 MB)
  u16* WkT    = (u16*)(ob + (152u << 20));
  u16* WvT    = (u16*)(ob + (176u << 20));
  u16* WoT    = (u16*)(ob + (200u << 20));
  u16* W1T    = (u16*)(ob + (224u << 20));           // 12 x [FF][E] (96 MB)
  u16* W2T    = (u16*)(ob + (320u << 20));           // 12 x [E][FF] (96 MB) -> ends 416M
  // --- d_ws: survives the head GEMM ---
  u16* hf     = (u16*)d_ws;                          // [BT,E] bf16 (8.39 MB)
  float* nll  = (float*)((char*)d_ws + 8388608);
  u16* WheadT = (u16*)((char*)d_ws + 8404992);       // [Vp][E] bf16 (103 MB)
  const size_t ws_need = 8404992u + (size_t)cVp * cE * 2u;
  const bool fast_head = ws_size >= ws_need;

  float* logits = (float*)d_out;
  float* loss = logits + (size_t)cBT * cV;

  const dim3 blk(256);
  const size_t e2 = (size_t)cE * cE, ef = (size_t)cE * cFF;

  // weight conversion (every call; ~200us)
  k_cvt_t<<<dim3(32, 32, cL), blk, 0, stream>>>(Wq, WqT, cE, cE, e2, e2);
  k_cvt_t<<<dim3(32, 32, cL), blk, 0, stream>>>(Wk, WkT, cE, cE, e2, e2);
  k_cvt_t<<<dim3(32, 32, cL), blk, 0, stream>>>(Wv, WvT, cE, cE, e2, e2);
  k_cvt_t<<<dim3(32, 32, cL), blk, 0, stream>>>(Wo, WoT, cE, cE, e2, e2);
  k_cvt_t<<<dim3(128, 32, cL), blk, 0, stream>>>(W1, W1T, cE, cFF, ef, ef);
  k_cvt_t<<<dim3(32, 128, cL), blk, 0, stream>>>(W2, W2T, cFF, cE, ef, ef);
  if (fast_head)
    k_cvt_t<<<dim3(cVp / 32, 32, 1), blk, 0, stream>>>(Wh, WheadT, cE, cV, 0, 0);

  k_embed<<<dim3(cBT), blk, 0, stream>>>(idx, tok, pos, x);
  for (int l = 0; l < cL; ++l) {
    k_ln<<<dim3(cBT), blk, 0, stream>>>(x, ln1g + l * cE, ln1b + l * cE, hb);
    k_gemm<0><<<dim3(32, 24), blk, 0, stream>>>(hb, WqT + l * e2, WkT + l * e2,
        WvT + l * e2, nullptr, qb, kb, vb, nullptr, cE, cE, 8);
    k_attn<<<dim3(16, 64), blk, 0, stream>>>(qb, kb, vb, abuf);
    k_gemm<1><<<dim3(32, 8), blk, 0, stream>>>(abuf, WoT + l * e2, nullptr, nullptr,
        bo + l * cE, nullptr, nullptr, nullptr, x, cE, cE, 8);
    k_ln<<<dim3(cBT), blk, 0, stream>>>(x, ln2g + l * cE, ln2b + l * cE, hb);
    k_gemm<2><<<dim3(32, 32), blk, 0, stream>>>(hb, W1T + l * ef, nullptr, nullptr,
        b1 + l * cFF, fbuf, nullptr, nullptr, nullptr, cE, cFF, 32);
    k_gemm<1><<<dim3(32, 8), blk, 0, stream>>>(fbuf, W2T + l * ef, nullptr, nullptr,
        b2 + l * cE, nullptr, nullptr, nullptr, x, cFF, cE, 8);
  }
  k_ln<<<dim3(cBT), blk, 0, stream>>>(x, lnfg, lnfb, hf);
  if (fast_head) {
    k_gemm<3><<<dim3(32, cVp / 128), blk, 0, stream>>>(hf, WheadT, nullptr, nullptr,
        bh, nullptr, nullptr, nullptr, logits, cE, cV, cVp / 128);
  } else {
    k_gemm_legacy3<<<dim3(393, 32), blk, 0, stream>>>(hf, Wh, bh, logits, cBT, cV, cE);
  }
  k_nll<<<dim3(cBT), blk, 0, stream>>>(logits, tgt, nll);
  k_loss<<<dim3(1), blk, 0, stream>>>(nll, loss);
}

// Round 3
// 5332.304 us; speedup vs baseline: 1.6218x; 1.1244x over previous
//
#include <hip/hip_runtime.h>
#include <cstdint>
#include <cstddef>

typedef unsigned short u16;
typedef __bf16 bf16x8 __attribute__((ext_vector_type(8)));
typedef float f32x4 __attribute__((ext_vector_type(4)));
typedef unsigned short u16x8 __attribute__((ext_vector_type(8)));
typedef unsigned short u16x4 __attribute__((ext_vector_type(4)));

constexpr int cV  = 50257;
constexpr int cVp = 50304;   // padded to 128
constexpr int cT  = 1024;
constexpr int cE  = 1024;
constexpr int cL  = 12;
constexpr int cFF = 4096;
constexpr int cBT = 4096;    // B*T

__device__ __forceinline__ u16 f2bf(float f) {
  union { float f; unsigned u; } x; x.f = f;
  unsigned r = x.u + 0x7fffu + ((x.u >> 16) & 1u);   // RNE
  return (u16)(r >> 16);
}

// async global->LDS, 16B per lane. dest must be linear in lane order.
__device__ __forceinline__ void gload16(const void* g, void* l) {
  __builtin_amdgcn_global_load_lds(
      (const __attribute__((address_space(1))) void*)g,
      (__attribute__((address_space(3))) void*)l, 16, 0, 0);
}

// XOR swizzle for 128B-wide LDS rows: permute 16B chunks within the row.
// byte = row*128 + swzoff(row, chunk) + (col&7)*2 ; chunk = col>>3.
__device__ __forceinline__ int swzoff(int row, int chunk) {
  return ((chunk ^ (row & 7) ^ ((row >> 3) & 7)) << 4);
}

// ---------------- embedding ----------------
__global__ __launch_bounds__(256) void k_embed(const int* __restrict__ idx,
    const float* __restrict__ tok, const float* __restrict__ pos,
    float* __restrict__ x) {
  const int row = blockIdx.x;
  const int t = row & (cT - 1);
  const int tk = idx[row];
  const float4* tv = (const float4*)(tok + (size_t)tk * cE);
  const float4* pv = (const float4*)(pos + (size_t)t * cE);
  float4* xv = (float4*)(x + (size_t)row * cE);
  const int i = threadIdx.x;
  float4 a = tv[i];
  float4 p = pv[i];
  a.x += p.x; a.y += p.y; a.z += p.z; a.w += p.w;
  xv[i] = a;
}

// ---------------- layernorm (f32 in -> bf16 out) ----------------
__global__ __launch_bounds__(256) void k_ln(const float* __restrict__ x,
    const float* __restrict__ gw, const float* __restrict__ bw,
    u16* __restrict__ out) {
  const int row = blockIdx.x;
  const int t = threadIdx.x;
  const float4 v = ((const float4*)(x + (size_t)row * cE))[t];
  float s1 = v.x + v.y + v.z + v.w;
  float s2 = v.x * v.x + v.y * v.y + v.z * v.z + v.w * v.w;
  #pragma unroll
  for (int off = 32; off; off >>= 1) {
    s1 += __shfl_xor(s1, off);
    s2 += __shfl_xor(s2, off);
  }
  __shared__ float red[8];
  const int wid = t >> 6;
  if ((t & 63) == 0) { red[wid] = s1; red[4 + wid] = s2; }
  __syncthreads();
  s1 = red[0] + red[1] + red[2] + red[3];
  s2 = red[4] + red[5] + red[6] + red[7];
  const float mean = s1 * (1.0f / cE);
  const float var = s2 * (1.0f / cE) - mean * mean;
  const float rs = rsqrtf(var + 1e-5f);
  const float4 g4 = ((const float4*)gw)[t];
  const float4 b4 = ((const float4*)bw)[t];
  u16x4 o;
  o[0] = f2bf((v.x - mean) * rs * g4.x + b4.x);
  o[1] = f2bf((v.y - mean) * rs * g4.y + b4.y);
  o[2] = f2bf((v.z - mean) * rs * g4.z + b4.z);
  o[3] = f2bf((v.w - mean) * rs * g4.w + b4.w);
  *(u16x4*)(out + (size_t)row * cE + t * 4) = o;
}

// ---------------- weight convert+transpose: f32[K][N] -> bf16[N][K] ----------------
__global__ __launch_bounds__(256) void k_cvt_t(const float* __restrict__ src,
    u16* __restrict__ dst, int K, int Nsrc, size_t sstride, size_t dstride) {
  __shared__ float tile[32][33];
  const float* s = src + blockIdx.z * sstride;
  u16* d = dst + blockIdx.z * dstride;
  const int n0 = blockIdx.x * 32, k0 = blockIdx.y * 32;
  const int t = threadIdx.x;
  const int c = t & 31, r0 = t >> 5;
  #pragma unroll
  for (int i = 0; i < 4; ++i) {
    const int kl = r0 + i * 8;
    const int n = n0 + c;
    tile[kl][c] = (n < Nsrc) ? s[(size_t)(k0 + kl) * Nsrc + n] : 0.0f;
  }
  __syncthreads();
  #pragma unroll
  for (int i = 0; i < 4; ++i) {
    const int nl = r0 + i * 8;
    d[(size_t)(n0 + nl) * K + k0 + c] = f2bf(tile[c][nl]);
  }
}

// ---------------- GEMM: C[M,Nout] = A[M][K](bf16) @ Bt[N][K](bf16)^T ----------------
// m97 structure: 128x128 tile, BK=32, global_load_lds w16, ds_read_b128 frags.
// EPI: 0 bf16 out (QKV, sel in y) | 1 f32 residual += | 2 bf16 gelu
//      3 f32 head + fused softmax partials | 4 f32 head plain (ragged)
template<int EPI>
__global__ __launch_bounds__(256) void k_gemm(
    const u16* __restrict__ A,
    const u16* __restrict__ Bt0, const u16* __restrict__ Bt1,
    const u16* __restrict__ Bt2, const float* __restrict__ bias,
    u16* __restrict__ o0, u16* __restrict__ o1, u16* __restrict__ o2,
    float* __restrict__ of, int K, int Nout, int ntile,
    float* __restrict__ pm, float* __restrict__ ps) {
  __shared__ u16 Al[128 * 32];
  __shared__ u16 Bl[128 * 32];
  const int tid = threadIdx.x;
  const int lane = tid & 63;
  const int wid = tid >> 6;
  const int bm = blockIdx.x;
  const int sel = (int)blockIdx.y / ntile;
  const int bn = (int)blockIdx.y - sel * ntile;
  const u16* Bt = (sel == 0) ? Bt0 : ((sel == 1) ? Bt1 : Bt2);
  u16* obf = (sel == 0) ? o0 : ((sel == 1) ? o1 : o2);
  const int wr = wid >> 1, wc = wid & 1;
  const int l15 = lane & 15, lg = lane >> 4;

  f32x4 acc[4][4];
  #pragma unroll
  for (int i = 0; i < 4; ++i)
    #pragma unroll
    for (int j = 0; j < 4; ++j) { f32x4 z = {0.f,0.f,0.f,0.f}; acc[i][j] = z; }

  const u16* Ab = A + (size_t)(bm * 128) * K;
  const u16* Bb = Bt + (size_t)(bn * 128) * K;
  const int srow = tid >> 2;
  const int scol = (tid & 3) * 8;
  char* AlB = (char*)Al;
  char* BlB = (char*)Bl;

  for (int kt = 0; kt < K; kt += 32) {
    gload16(Ab + (size_t)srow * K + kt + scol,        AlB + tid * 16);
    gload16(Ab + (size_t)(srow + 64) * K + kt + scol, AlB + 4096 + tid * 16);
    gload16(Bb + (size_t)srow * K + kt + scol,        BlB + tid * 16);
    gload16(Bb + (size_t)(srow + 64) * K + kt + scol, BlB + 4096 + tid * 16);
    __syncthreads();

    bf16x8 af[4], bf[4];
    #pragma unroll
    for (int mi = 0; mi < 4; ++mi)
      af[mi] = *(const bf16x8*)(Al + (wr * 64 + mi * 16 + l15) * 32 + lg * 8);
    #pragma unroll
    for (int ni = 0; ni < 4; ++ni)
      bf[ni] = *(const bf16x8*)(Bl + (wc * 64 + ni * 16 + l15) * 32 + lg * 8);
    #pragma unroll
    for (int ni = 0; ni < 4; ++ni)
      #pragma unroll
      for (int mi = 0; mi < 4; ++mi)
        acc[mi][ni] = __builtin_amdgcn_mfma_f32_16x16x32_bf16(af[mi], bf[ni], acc[mi][ni], 0, 0, 0);
    __syncthreads();
  }

  if constexpr (EPI == 3) {
    // head epilogue: write logits + per-(row,tile) softmax partials
    float rmax[4][4], rsum[4][4];
    #pragma unroll
    for (int mi = 0; mi < 4; ++mi) {
      const int grow = bm * 128 + wr * 64 + mi * 16 + lg * 4;
      #pragma unroll
      for (int r = 0; r < 4; ++r) rmax[mi][r] = -1e30f;
      #pragma unroll
      for (int ni = 0; ni < 4; ++ni) {
        const int gcol = bn * 128 + wc * 64 + ni * 16 + l15;
        const bool ok = gcol < Nout;
        const float bb = ok ? bias[gcol] : 0.0f;
        #pragma unroll
        for (int r = 0; r < 4; ++r) {
          const float v = ok ? (acc[mi][ni][r] + bb) : -1e30f;
          acc[mi][ni][r] = v;
          if (ok) of[(size_t)(grow + r) * Nout + gcol] = v;
          rmax[mi][r] = fmaxf(rmax[mi][r], v);
        }
      }
    }
    #pragma unroll
    for (int mi = 0; mi < 4; ++mi)
      #pragma unroll
      for (int r = 0; r < 4; ++r) {
        float m = rmax[mi][r];
        #pragma unroll
        for (int off = 1; off < 16; off <<= 1) m = fmaxf(m, __shfl_xor(m, off));
        rmax[mi][r] = m;
        float s = 0.f;
        #pragma unroll
        for (int ni = 0; ni < 4; ++ni) s += __expf(acc[mi][ni][r] - m);
        #pragma unroll
        for (int off = 1; off < 16; off <<= 1) s += __shfl_xor(s, off);
        rsum[mi][r] = s;
      }
    __shared__ float pb[128][2][2];
    if (l15 == 0) {
      #pragma unroll
      for (int mi = 0; mi < 4; ++mi)
        #pragma unroll
        for (int r = 0; r < 4; ++r) {
          const int lrow = wr * 64 + mi * 16 + lg * 4 + r;
          pb[lrow][wc][0] = rmax[mi][r];
          pb[lrow][wc][1] = rsum[mi][r];
        }
    }
    __syncthreads();
    if (tid < 128) {
      const float m0 = pb[tid][0][0], s0 = pb[tid][0][1];
      const float m1 = pb[tid][1][0], s1 = pb[tid][1][1];
      const float M = fmaxf(m0, m1);
      const float S = s0 * __expf(m0 - M) + s1 * __expf(m1 - M);
      const size_t grow = (size_t)(bm * 128 + tid);
      pm[grow * ntile + bn] = M;
      ps[grow * ntile + bn] = S;
    }
  } else {
    #pragma unroll
    for (int mi = 0; mi < 4; ++mi) {
      const int grow = bm * 128 + wr * 64 + mi * 16 + lg * 4;
      #pragma unroll
      for (int ni = 0; ni < 4; ++ni) {
        const int gcol = bn * 128 + wc * 64 + ni * 16 + l15;
        #pragma unroll
        for (int r = 0; r < 4; ++r) {
          const float a = acc[mi][ni][r];
          const size_t oidx = (size_t)(grow + r) * Nout + gcol;
          if constexpr (EPI == 0) {
            obf[oidx] = f2bf(a);
          } else if constexpr (EPI == 1) {
            of[oidx] += a + bias[gcol];
          } else if constexpr (EPI == 2) {
            const float gv = a + bias[gcol];
            obf[oidx] = f2bf(0.5f * gv * (1.0f + erff(gv * 0.70710678118f)));
          } else {
            if (gcol < Nout) of[oidx] = a + bias[gcol];
          }
        }
      }
    }
  }
}

// ---------------- small-M GEMM: 64x128 tile, EPI1 (residual +=) ----------------
// For M=4096,N=1024 shapes: 512 blocks (2/CU) instead of 256 (1/CU).
__global__ __launch_bounds__(256) void k_gemm_s(
    const u16* __restrict__ A, const u16* __restrict__ Bt,
    const float* __restrict__ bias, float* __restrict__ of, int K, int Nout) {
  __shared__ u16 Al[64 * 32];
  __shared__ u16 Bl[128 * 32];
  const int tid = threadIdx.x;
  const int lane = tid & 63;
  const int wid = tid >> 6;
  const int bm = blockIdx.x;
  const int bn = blockIdx.y;
  const int wr = wid >> 1, wc = wid & 1;
  const int l15 = lane & 15, lg = lane >> 4;

  f32x4 acc[2][4];
  #pragma unroll
  for (int i = 0; i < 2; ++i)
    #pragma unroll
    for (int j = 0; j < 4; ++j) { f32x4 z = {0.f,0.f,0.f,0.f}; acc[i][j] = z; }

  const u16* Ab = A + (size_t)(bm * 64) * K;
  const u16* Bb = Bt + (size_t)(bn * 128) * K;
  const int srow = tid >> 2;
  const int scol = (tid & 3) * 8;
  char* AlB = (char*)Al;
  char* BlB = (char*)Bl;

  for (int kt = 0; kt < K; kt += 32) {
    gload16(Ab + (size_t)srow * K + kt + scol,        AlB + tid * 16);
    gload16(Bb + (size_t)srow * K + kt + scol,        BlB + tid * 16);
    gload16(Bb + (size_t)(srow + 64) * K + kt + scol, BlB + 4096 + tid * 16);
    __syncthreads();

    bf16x8 af[2], bf[4];
    #pragma unroll
    for (int mi = 0; mi < 2; ++mi)
      af[mi] = *(const bf16x8*)(Al + (wr * 32 + mi * 16 + l15) * 32 + lg * 8);
    #pragma unroll
    for (int ni = 0; ni < 4; ++ni)
      bf[ni] = *(const bf16x8*)(Bl + (wc * 64 + ni * 16 + l15) * 32 + lg * 8);
    #pragma unroll
    for (int ni = 0; ni < 4; ++ni)
      #pragma unroll
      for (int mi = 0; mi < 2; ++mi)
        acc[mi][ni] = __builtin_amdgcn_mfma_f32_16x16x32_bf16(af[mi], bf[ni], acc[mi][ni], 0, 0, 0);
    __syncthreads();
  }

  #pragma unroll
  for (int mi = 0; mi < 2; ++mi) {
    const int grow = bm * 64 + wr * 32 + mi * 16 + lg * 4;
    #pragma unroll
    for (int ni = 0; ni < 4; ++ni) {
      const int gcol = bn * 128 + wc * 64 + ni * 16 + l15;
      #pragma unroll
      for (int r = 0; r < 4; ++r)
        of[(size_t)(grow + r) * Nout + gcol] += acc[mi][ni][r] + bias[gcol];
    }
  }
}

// ---------------- legacy head GEMM (f32 B, used only if d_ws too small) ----------------
__global__ __launch_bounds__(256) void k_gemm_legacy3(
    const u16* __restrict__ A, const float* __restrict__ B0,
    const float* __restrict__ bias, float* __restrict__ of,
    int M, int N, int K) {
  __shared__ u16 Al[128 * 32];
  __shared__ u16 Bl[32 * 128];
  const int tid = threadIdx.x;
  const int lane = tid & 63;
  const int wid = tid >> 6;
  const int bn = blockIdx.x;
  const int bm = blockIdx.y;
  const int wr = wid >> 1, wc = wid & 1;
  const int l15 = lane & 15, lg = lane >> 4;
  f32x4 acc[4][4];
  #pragma unroll
  for (int i = 0; i < 4; ++i)
    #pragma unroll
    for (int j = 0; j < 4; ++j) { f32x4 z = {0.f,0.f,0.f,0.f}; acc[i][j] = z; }
  const u16* Abase = A + (size_t)(bm * 128) * K;
  const int ar0 = tid >> 2;
  const int ac0 = (tid & 3) * 8;
  const int brow = tid >> 3;
  const int bc0 = (tid & 7) * 16;
  for (int kt = 0; kt < K; kt += 32) {
    *(u16x8*)(Al + ar0 * 32 + ac0) =
        *(const u16x8*)(Abase + (size_t)ar0 * K + kt + ac0);
    *(u16x8*)(Al + (ar0 + 64) * 32 + ac0) =
        *(const u16x8*)(Abase + (size_t)(ar0 + 64) * K + kt + ac0);
    {
      const float* bsrc = B0 + (size_t)(kt + brow) * N + bn * 128 + bc0;
      alignas(16) u16 tmp[16];
      const int colbase = bn * 128 + bc0;
      #pragma unroll
      for (int q = 0; q < 16; ++q)
        tmp[q] = f2bf((colbase + q < N) ? bsrc[q] : 0.0f);
      *(u16x8*)(Bl + brow * 128 + bc0) = *(const u16x8*)tmp;
      *(u16x8*)(Bl + brow * 128 + bc0 + 8) = *(const u16x8*)(tmp + 8);
    }
    __syncthreads();
    bf16x8 af[4];
    #pragma unroll
    for (int mi = 0; mi < 4; ++mi)
      af[mi] = *(const bf16x8*)(Al + (wr * 64 + mi * 16 + l15) * 32 + lg * 8);
    #pragma unroll
    for (int ni = 0; ni < 4; ++ni) {
      u16x8 tv;
      #pragma unroll
      for (int i = 0; i < 8; ++i)
        tv[i] = Bl[(lg * 8 + i) * 128 + wc * 64 + ni * 16 + l15];
      const bf16x8 bfr = __builtin_bit_cast(bf16x8, tv);
      #pragma unroll
      for (int mi = 0; mi < 4; ++mi)
        acc[mi][ni] = __builtin_amdgcn_mfma_f32_16x16x32_bf16(af[mi], bfr, acc[mi][ni], 0, 0, 0);
    }
    __syncthreads();
  }
  #pragma unroll
  for (int mi = 0; mi < 4; ++mi) {
    const int grow = bm * 128 + wr * 64 + mi * 16 + lg * 4;
    #pragma unroll
    for (int ni = 0; ni < 4; ++ni) {
      const int gcol = bn * 128 + wc * 64 + ni * 16 + l15;
      #pragma unroll
      for (int r = 0; r < 4; ++r)
        if (gcol < N) of[(size_t)(grow + r) * N + gcol] = acc[mi][ni][r] + bias[gcol];
    }
  }
}

// ---------------- causal flash attention (XOR-swizzled LDS) ----------------
__global__ __launch_bounds__(256, 2) void k_attn(
    const u16* __restrict__ qg, const u16* __restrict__ kg,
    const u16* __restrict__ vg, u16* __restrict__ og) {
  __shared__ u16 Kl[64 * 64];        // [krow][d], swizzled 16B chunks
  __shared__ u16 Vt[64 * 64];        // [d][krow], swizzled
  __shared__ u16 Pl[4][16 * 64];     // per-wave P, swizzled
  const int tid = threadIdx.x;
  const int lane = tid & 63;
  const int w = tid >> 6;
  const int qt = blockIdx.x;
  const int bh = blockIdx.y;
  const int b = bh >> 4, h = bh & 15;
  const int l15 = lane & 15, lg = lane >> 4;
  char* KlB = (char*)Kl;
  char* VtB = (char*)Vt;
  char* PlB = (char*)(Pl[w]);

  const size_t qrow0 = (size_t)b * cT + qt * 64 + w * 16;
  bf16x8 aq[2];
  #pragma unroll
  for (int c = 0; c < 2; ++c)
    aq[c] = *(const bf16x8*)(qg + (qrow0 + l15) * cE + h * 64 + c * 32 + lg * 8);

  f32x4 acco[4];
  #pragma unroll
  for (int j = 0; j < 4; ++j) { f32x4 z = {0.f,0.f,0.f,0.f}; acco[j] = z; }
  float mrun[4], lrun[4];
  #pragma unroll
  for (int r = 0; r < 4; ++r) { mrun[r] = -1e30f; lrun[r] = 0.f; }

  for (int kt = 0; kt <= qt; ++kt) {
    const size_t krow0 = (size_t)b * cT + kt * 64;
    #pragma unroll
    for (int u = 0; u < 2; ++u) {
      const int un = tid + u * 256;
      const int rr = un >> 3, c8 = (un & 7) * 8;
      *(u16x8*)(KlB + rr * 128 + swzoff(rr, c8 >> 3)) =
          *(const u16x8*)(kg + (krow0 + rr) * cE + h * 64 + c8);
      const u16x8 vv = *(const u16x8*)(vg + (krow0 + rr) * cE + h * 64 + c8);
      #pragma unroll
      for (int i = 0; i < 8; ++i)
        *(u16*)(VtB + (c8 + i) * 128 + swzoff(c8 + i, rr >> 3) + (rr & 7) * 2) = vv[i];
    }
    __syncthreads();

    f32x4 s[4];
    #pragma unroll
    for (int j = 0; j < 4; ++j) { f32x4 z = {0.f,0.f,0.f,0.f}; s[j] = z; }
    #pragma unroll
    for (int c = 0; c < 2; ++c) {
      #pragma unroll
      for (int j = 0; j < 4; ++j) {
        const int n = j * 16 + l15;
        const bf16x8 kb2 = *(const bf16x8*)(KlB + n * 128 + swzoff(n, c * 4 + lg));
        s[j] = __builtin_amdgcn_mfma_f32_16x16x32_bf16(aq[c], kb2, s[j], 0, 0, 0);
      }
    }

    float sv[4][4];
    const bool diag = (kt == qt);
    #pragma unroll
    for (int j = 0; j < 4; ++j)
      #pragma unroll
      for (int r = 0; r < 4; ++r) {
        float xs = s[j][r] * 0.125f;
        if (diag && (j * 16 + l15) > (w * 16 + lg * 4 + r)) xs = -1e30f;
        sv[j][r] = xs;
      }

    float corr[4];
    #pragma unroll
    for (int r = 0; r < 4; ++r) {
      float mx = fmaxf(fmaxf(sv[0][r], sv[1][r]), fmaxf(sv[2][r], sv[3][r]));
      #pragma unroll
      for (int off = 1; off < 16; off <<= 1) mx = fmaxf(mx, __shfl_xor(mx, off));
      const float mnew = fmaxf(mrun[r], mx);
      corr[r] = __expf(mrun[r] - mnew);
      float rs = 0.f;
      #pragma unroll
      for (int j = 0; j < 4; ++j) {
        const float p = __expf(sv[j][r] - mnew);
        sv[j][r] = p;
        rs += p;
      }
      #pragma unroll
      for (int off = 1; off < 16; off <<= 1) rs += __shfl_xor(rs, off);
      lrun[r] = lrun[r] * corr[r] + rs;
      mrun[r] = mnew;
    }

    #pragma unroll
    for (int j = 0; j < 4; ++j)
      #pragma unroll
      for (int r = 0; r < 4; ++r) {
        const int qr = lg * 4 + r, kc = j * 16 + l15;
        *(u16*)(PlB + qr * 128 + swzoff(qr, kc >> 3) + (kc & 7) * 2) = f2bf(sv[j][r]);
        acco[j][r] *= corr[r];
      }

    #pragma unroll
    for (int c = 0; c < 2; ++c) {
      const bf16x8 pa = *(const bf16x8*)(PlB + l15 * 128 + swzoff(l15, c * 4 + lg));
      #pragma unroll
      for (int j = 0; j < 4; ++j) {
        const int n = j * 16 + l15;
        const bf16x8 vb2 = *(const bf16x8*)(VtB + n * 128 + swzoff(n, c * 4 + lg));
        acco[j] = __builtin_amdgcn_mfma_f32_16x16x32_bf16(pa, vb2, acco[j], 0, 0, 0);
      }
    }
    __syncthreads();
  }

  #pragma unroll
  for (int j = 0; j < 4; ++j)
    #pragma unroll
    for (int r = 0; r < 4; ++r)
      og[(qrow0 + lg * 4 + r) * cE + h * 64 + j * 16 + l15] = f2bf(acco[j][r] / lrun[r]);
}

// ---------------- NLL from per-tile partials ----------------
__global__ __launch_bounds__(256) void k_nll2(const float* __restrict__ pm,
    const float* __restrict__ ps, const float* __restrict__ logits,
    const int* __restrict__ tgt, float* __restrict__ nll, int NT) {
  const int row = blockIdx.x * 4 + (threadIdx.x >> 6);
  const int lane = threadIdx.x & 63;
  float m = -1e30f, s = 0.f;
  for (int i = lane; i < NT; i += 64) {
    const float m2 = pm[(size_t)row * NT + i];
    const float s2 = ps[(size_t)row * NT + i];
    const float M = fmaxf(m, m2);
    s = s * __expf(m - M) + s2 * __expf(m2 - M);
    m = M;
  }
  #pragma unroll
  for (int off = 1; off < 64; off <<= 1) {
    const float m2 = __shfl_xor(m, off);
    const float s2 = __shfl_xor(s, off);
    const float M = fmaxf(m, m2);
    s = s * __expf(m - M) + s2 * __expf(m2 - M);
    m = M;
  }
  if (lane == 0)
    nll[row] = logf(s) + m - logits[(size_t)row * cV + tgt[row]];
}

// ---------------- per-row NLL over V (fallback) ----------------
__global__ __launch_bounds__(256) void k_nll(const float* __restrict__ logits,
    const int* __restrict__ tgt, float* __restrict__ nll) {
  const int row = blockIdx.x;
  const float* lp = logits + (size_t)row * cV;
  const int t = threadIdx.x;
  __shared__ float red[8];
  const int wid = t >> 6, lane = t & 63;
  float mx = -1e30f;
  for (int i = t; i < cV; i += 256) mx = fmaxf(mx, lp[i]);
  #pragma unroll
  for (int off = 32; off; off >>= 1) mx = fmaxf(mx, __shfl_xor(mx, off));
  if (lane == 0) red[wid] = mx;
  __syncthreads();
  mx = fmaxf(fmaxf(red[0], red[1]), fmaxf(red[2], red[3]));
  float s = 0.f;
  for (int i = t; i < cV; i += 256) s += __expf(lp[i] - mx);
  #pragma unroll
  for (int off = 32; off; off >>= 1) s += __shfl_xor(s, off);
  if (lane == 0) red[4 + wid] = s;
  __syncthreads();
  if (t == 0) {
    s = red[4] + red[5] + red[6] + red[7];
    nll[row] = logf(s) + mx - lp[tgt[row]];
  }
}

__global__ __launch_bounds__(256) void k_loss(const float* __restrict__ nll,
    float* __restrict__ out) {
  const int t = threadIdx.x;
  float s = 0.f;
  for (int i = t; i < cBT; i += 256) s += nll[i];
  #pragma unroll
  for (int off = 32; off; off >>= 1) s += __shfl_xor(s, off);
  __shared__ float red[4];
  if ((t & 63) == 0) red[t >> 6] = s;
  __syncthreads();
  if (t == 0) out[0] = (red[0] + red[1] + red[2] + red[3]) * (1.0f / cBT);
}

extern "C" void kernel_launch(void* const* d_in, const int* in_sizes, int n_in,
                              void* d_out, int out_size, void* d_ws, size_t ws_size,
                              hipStream_t stream) {
  const int*   idx  = (const int*)d_in[0];
  const int*   tgt  = (const int*)d_in[1];
  const float* tok  = (const float*)d_in[2];
  const float* pos  = (const float*)d_in[3];
  const float* Wq   = (const float*)d_in[4];
  const float* Wk   = (const float*)d_in[5];
  const float* Wv   = (const float*)d_in[6];
  const float* Wo   = (const float*)d_in[7];
  const float* bo   = (const float*)d_in[8];
  const float* ln1g = (const float*)d_in[9];
  const float* ln1b = (const float*)d_in[10];
  const float* ln2g = (const float*)d_in[11];
  const float* ln2b = (const float*)d_in[12];
  const float* W1   = (const float*)d_in[13];
  const float* b1   = (const float*)d_in[14];
  const float* W2   = (const float*)d_in[15];
  const float* b2   = (const float*)d_in[16];
  const float* lnfg = (const float*)d_in[17];
  const float* lnfb = (const float*)d_in[18];
  const float* Wh   = (const float*)d_in[19];
  const float* bh   = (const float*)d_in[20];

  // --- d_out scratch plan (all dead before head GEMM overwrites d_out) ---
  char* ob = (char*)d_out;
  float* x    = (float*)ob;                          // [BT,E] f32, 16 MB
  u16* hb     = (u16*)(ob + (16u << 20));
  u16* qb     = (u16*)(ob + (24u << 20));
  u16* kb     = (u16*)(ob + (32u << 20));
  u16* vb     = (u16*)(ob + (40u << 20));
  u16* abuf   = (u16*)(ob + (48u << 20));
  u16* fbuf   = (u16*)(ob + (56u << 20));            // [BT,FF] bf16 -> ends 88M
  u16* WqT    = (u16*)(ob + (128u << 20));
  u16* WkT    = (u16*)(ob + (152u << 20));
  u16* WvT    = (u16*)(ob + (176u << 20));
  u16* WoT    = (u16*)(ob + (200u << 20));
  u16* W1T    = (u16*)(ob + (224u << 20));
  u16* W2T    = (u16*)(ob + (320u << 20));           // ends 416M
  // --- d_ws layout ---
  u16* hf     = (u16*)d_ws;                          // 8.39 MB
  float* nll  = (float*)((char*)d_ws + 8388608);
  u16* WheadT = (u16*)((char*)d_ws + 8404992);       // 103.0 MB
  const size_t whead_end = 8404992u + (size_t)cVp * cE * 2u;   // 111,427,584
  float* pmax = (float*)((char*)d_ws + whead_end);
  float* psum = (float*)((char*)d_ws + whead_end + (size_t)cBT * 393 * 4);
  const size_t ws_need  = whead_end;
  const size_t ws_need2 = whead_end + 2u * (size_t)cBT * 393 * 4;   // 124.3 MB
  const bool fast_head = ws_size >= ws_need;
  const bool fused_nll = ws_size >= ws_need2;

  float* logits = (float*)d_out;
  float* loss = logits + (size_t)cBT * cV;

  const dim3 blk(256);
  const size_t e2 = (size_t)cE * cE, ef = (size_t)cE * cFF;

  k_cvt_t<<<dim3(32, 32, cL), blk, 0, stream>>>(Wq, WqT, cE, cE, e2, e2);
  k_cvt_t<<<dim3(32, 32, cL), blk, 0, stream>>>(Wk, WkT, cE, cE, e2, e2);
  k_cvt_t<<<dim3(32, 32, cL), blk, 0, stream>>>(Wv, WvT, cE, cE, e2, e2);
  k_cvt_t<<<dim3(32, 32, cL), blk, 0, stream>>>(Wo, WoT, cE, cE, e2, e2);
  k_cvt_t<<<dim3(128, 32, cL), blk, 0, stream>>>(W1, W1T, cE, cFF, ef, ef);
  k_cvt_t<<<dim3(32, 128, cL), blk, 0, stream>>>(W2, W2T, cFF, cE, ef, ef);
  if (fast_head)
    k_cvt_t<<<dim3(cVp / 32, 32, 1), blk, 0, stream>>>(Wh, WheadT, cE, cV, 0, 0);

  k_embed<<<dim3(cBT), blk, 0, stream>>>(idx, tok, pos, x);
  for (int l = 0; l < cL; ++l) {
    k_ln<<<dim3(cBT), blk, 0, stream>>>(x, ln1g + l * cE, ln1b + l * cE, hb);
    k_gemm<0><<<dim3(32, 24), blk, 0, stream>>>(hb, WqT + l * e2, WkT + l * e2,
        WvT + l * e2, nullptr, qb, kb, vb, nullptr, cE, cE, 8, nullptr, nullptr);
    k_attn<<<dim3(16, 64), blk, 0, stream>>>(qb, kb, vb, abuf);
    k_gemm_s<<<dim3(64, 8), blk, 0, stream>>>(abuf, WoT + l * e2, bo + l * cE, x, cE, cE);
    k_ln<<<dim3(cBT), blk, 0, stream>>>(x, ln2g + l * cE, ln2b + l * cE, hb);
    k_gemm<2><<<dim3(32, 32), blk, 0, stream>>>(hb, W1T + l * ef, nullptr, nullptr,
        b1 + l * cFF, fbuf, nullptr, nullptr, nullptr, cE, cFF, 32, nullptr, nullptr);
    k_gemm_s<<<dim3(64, 8), blk, 0, stream>>>(fbuf, W2T + l * ef, b2 + l * cE, x, cFF, cE);
  }
  k_ln<<<dim3(cBT), blk, 0, stream>>>(x, lnfg, lnfb, hf);
  if (fast_head) {
    if (fused_nll) {
      k_gemm<3><<<dim3(32, cVp / 128), blk, 0, stream>>>(hf, WheadT, nullptr, nullptr,
          bh, nullptr, nullptr, nullptr, logits, cE, cV, cVp / 128, pmax, psum);
      k_nll2<<<dim3(cBT / 4), blk, 0, stream>>>(pmax, psum, logits, tgt, nll, cVp / 128);
    } else {
      k_gemm<4><<<dim3(32, cVp / 128), blk, 0, stream>>>(hf, WheadT, nullptr, nullptr,
          bh, nullptr, nullptr, nullptr, logits, cE, cV, cVp / 128, nullptr, nullptr);
      k_nll<<<dim3(cBT), blk, 0, stream>>>(logits, tgt, nll);
    }
  } else {
    k_gemm_legacy3<<<dim3(393, 32), blk, 0, stream>>>(hf, Wh, bh, logits, cBT, cV, cE);
    k_nll<<<dim3(cBT), blk, 0, stream>>>(logits, tgt, nll);
  }
  k_loss<<<dim3(1), blk, 0, stream>>>(nll, loss);
}

// Round 4
// 5032.591 us; speedup vs baseline: 1.7184x; 1.0596x over previous
//
#include <hip/hip_runtime.h>
#include <cstdint>
#include <cstddef>

typedef unsigned short u16;
typedef __bf16 bf16x8 __attribute__((ext_vector_type(8)));
typedef float f32x4 __attribute__((ext_vector_type(4)));
typedef unsigned short u16x8 __attribute__((ext_vector_type(8)));
typedef unsigned short u16x4 __attribute__((ext_vector_type(4)));

constexpr int cV  = 50257;
constexpr int cVp = 50432;   // padded to 256
constexpr int cNT = cVp / 256;  // 197 head n-tiles
constexpr int cT  = 1024;
constexpr int cE  = 1024;
constexpr int cL  = 12;
constexpr int cFF = 4096;
constexpr int cBT = 4096;    // B*T

__device__ __forceinline__ u16 f2bf(float f) {
  union { float f; unsigned u; } x; x.f = f;
  unsigned r = x.u + 0x7fffu + ((x.u >> 16) & 1u);   // RNE
  return (u16)(r >> 16);
}

// async global->LDS, 16B per lane. dest must be linear in lane order.
__device__ __forceinline__ void gload16(const void* g, void* l) {
  __builtin_amdgcn_global_load_lds(
      (const __attribute__((address_space(1))) void*)g,
      (__attribute__((address_space(3))) void*)l, 16, 0, 0);
}

// XOR swizzle for 128B-wide LDS rows (attn): permute 16B chunks within row.
__device__ __forceinline__ int swzoff(int row, int chunk) {
  return ((chunk ^ (row & 7) ^ ((row >> 3) & 7)) << 4);
}

// ---------------- embedding ----------------
__global__ __launch_bounds__(256) void k_embed(const int* __restrict__ idx,
    const float* __restrict__ tok, const float* __restrict__ pos,
    float* __restrict__ x) {
  const int row = blockIdx.x;
  const int t = row & (cT - 1);
  const int tk = idx[row];
  const float4* tv = (const float4*)(tok + (size_t)tk * cE);
  const float4* pv = (const float4*)(pos + (size_t)t * cE);
  float4* xv = (float4*)(x + (size_t)row * cE);
  const int i = threadIdx.x;
  float4 a = tv[i];
  float4 p = pv[i];
  a.x += p.x; a.y += p.y; a.z += p.z; a.w += p.w;
  xv[i] = a;
}

// ---------------- layernorm (f32 in -> bf16 out) ----------------
__global__ __launch_bounds__(256) void k_ln(const float* __restrict__ x,
    const float* __restrict__ gw, const float* __restrict__ bw,
    u16* __restrict__ out) {
  const int row = blockIdx.x;
  const int t = threadIdx.x;
  const float4 v = ((const float4*)(x + (size_t)row * cE))[t];
  float s1 = v.x + v.y + v.z + v.w;
  float s2 = v.x * v.x + v.y * v.y + v.z * v.z + v.w * v.w;
  #pragma unroll
  for (int off = 32; off; off >>= 1) {
    s1 += __shfl_xor(s1, off);
    s2 += __shfl_xor(s2, off);
  }
  __shared__ float red[8];
  const int wid = t >> 6;
  if ((t & 63) == 0) { red[wid] = s1; red[4 + wid] = s2; }
  __syncthreads();
  s1 = red[0] + red[1] + red[2] + red[3];
  s2 = red[4] + red[5] + red[6] + red[7];
  const float mean = s1 * (1.0f / cE);
  const float var = s2 * (1.0f / cE) - mean * mean;
  const float rs = rsqrtf(var + 1e-5f);
  const float4 g4 = ((const float4*)gw)[t];
  const float4 b4 = ((const float4*)bw)[t];
  u16x4 o;
  o[0] = f2bf((v.x - mean) * rs * g4.x + b4.x);
  o[1] = f2bf((v.y - mean) * rs * g4.y + b4.y);
  o[2] = f2bf((v.z - mean) * rs * g4.z + b4.z);
  o[3] = f2bf((v.w - mean) * rs * g4.w + b4.w);
  *(u16x4*)(out + (size_t)row * cE + t * 4) = o;
}

// ---------------- weight convert+transpose: f32[K][N] -> bf16[N][K] ----------------
__global__ __launch_bounds__(256) void k_cvt_t(const float* __restrict__ src,
    u16* __restrict__ dst, int K, int Nsrc, size_t sstride, size_t dstride) {
  __shared__ float tile[32][33];
  const float* s = src + blockIdx.z * sstride;
  u16* d = dst + blockIdx.z * dstride;
  const int n0 = blockIdx.x * 32, k0 = blockIdx.y * 32;
  const int t = threadIdx.x;
  const int c = t & 31, r0 = t >> 5;
  #pragma unroll
  for (int i = 0; i < 4; ++i) {
    const int kl = r0 + i * 8;
    const int n = n0 + c;
    tile[kl][c] = (n < Nsrc) ? s[(size_t)(k0 + kl) * Nsrc + n] : 0.0f;
  }
  __syncthreads();
  #pragma unroll
  for (int i = 0; i < 4; ++i) {
    const int nl = r0 + i * 8;
    d[(size_t)(n0 + nl) * K + k0 + c] = f2bf(tile[c][nl]);
  }
}

// ============== 256x256 deep-pipelined GEMM (T2+T3+T4+T5) ==============
// C[M,Nout] = A[M][K](bf16) @ Bt[Npad][K](bf16)^T. BK=64, 512 thr = 8 waves
// (2M x 4N), per-wave 128x64 out. LDS 128KB: 2 bufs x (A 32K + B 32K), rows
// of 8x16B chunks, chunk XOR-swizzled by (row&7); global src pre-swizzled.
// Pipeline: tile t in buf[t&1]; phase A (mh=0) reads A-lo + all B, issues
// A-hi(t+1)->buf^1; phase B (mh=1) reads A-hi, issues {A-lo,B}(t+2)->buf.
// vmcnt(6) once per tile keeps 3 half-tiles (6 loads/thread) in flight.
// EPI: 0 = bf16 qkv (3 contiguous 8MB slabs), 2 = bf16 gelu, 3 = f32 head
// + fused softmax partials.
__device__ __forceinline__ void stage_half(const u16* __restrict__ Mb, int K,
    int kt, char* lds, int half, int tid) {
  #pragma unroll
  for (int p = 0; p < 2; ++p) {
    const int L = half * 1024 + p * 512 + tid;
    const int row = L >> 3, cc = L & 7;
    gload16(Mb + (size_t)row * K + kt + ((cc ^ (row & 7)) << 3),
            lds + (size_t)L * 16);
  }
}

template<int EPI>
__global__ __launch_bounds__(512) void k_gemm2(
    const u16* __restrict__ A, const u16* __restrict__ Bt,
    const float* __restrict__ bias, u16* __restrict__ obf,
    float* __restrict__ of, int K, int Nout, int ntile,
    float* __restrict__ pm, float* __restrict__ ps) {
  __shared__ __align__(16) char smem[131072];
  const int tid = threadIdx.x;
  const int lane = tid & 63;
  const int wid = tid >> 6;
  const int bm = blockIdx.x;
  const int bn = blockIdx.y;
  const int wm = wid >> 2, wn = wid & 3;
  const int l15 = lane & 15, lg = lane >> 4;

  f32x4 acc[8][4];
  #pragma unroll
  for (int i = 0; i < 8; ++i)
    #pragma unroll
    for (int j = 0; j < 4; ++j) { f32x4 z = {0.f,0.f,0.f,0.f}; acc[i][j] = z; }

  const u16* Ab = A + (size_t)(bm * 256) * K;
  const u16* Bb = Bt + (size_t)(bn * 256) * K;
  const int nt = K >> 6;

  // prologue: S1(0)->buf0, S2(0)->buf0, S1(1)->buf1  (14 loads/thread)
  {
    char* s0 = smem;
    char* s1 = smem + 65536;
    stage_half(Ab, K, 0, s0, 0, tid);
    stage_half(Bb, K, 0, s0 + 32768, 0, tid);
    stage_half(Bb, K, 0, s0 + 32768, 1, tid);
    stage_half(Ab, K, 0, s0, 1, tid);
    const int k1 = (nt > 1) ? 64 : 0;
    stage_half(Ab, K, k1, s1, 0, tid);
    stage_half(Bb, K, k1, s1 + 32768, 0, tid);
    stage_half(Bb, K, k1, s1 + 32768, 1, tid);
  }

  bf16x8 bfr[4][2];
  for (int t = 0; t < nt; ++t) {
    char* cs = smem + ((t & 1) << 16);
    char* co = smem + (((t & 1) ^ 1) << 16);
    const char* csB = cs + 32768;
    const int kn1 = (t + 1 < nt ? t + 1 : nt - 1) << 6;
    const int kn2 = (t + 2 < nt ? t + 2 : nt - 1) << 6;

    asm volatile("s_waitcnt vmcnt(6)" ::: "memory");
    __builtin_amdgcn_s_barrier();

    // ---- phase A: mh=0 ----
    bf16x8 af[4][2];
    #pragma unroll
    for (int mi = 0; mi < 4; ++mi) {
      const int row = wm * 128 + mi * 16 + l15;
      #pragma unroll
      for (int kk = 0; kk < 2; ++kk)
        af[mi][kk] = *(const bf16x8*)(cs + row * 128 + (((kk * 4 + lg) ^ (row & 7)) << 4));
    }
    #pragma unroll
    for (int ni = 0; ni < 4; ++ni) {
      const int rowB = wn * 64 + ni * 16 + l15;
      #pragma unroll
      for (int kk = 0; kk < 2; ++kk)
        bfr[ni][kk] = *(const bf16x8*)(csB + rowB * 128 + (((kk * 4 + lg) ^ (rowB & 7)) << 4));
    }
    stage_half(Ab, K, kn1, co, 1, tid);          // S2(t+1): A-hi
    __builtin_amdgcn_sched_barrier(0);
    __builtin_amdgcn_s_setprio(1);
    #pragma unroll
    for (int kk = 0; kk < 2; ++kk)
      #pragma unroll
      for (int ni = 0; ni < 4; ++ni)
        #pragma unroll
        for (int mi = 0; mi < 4; ++mi)
          acc[mi][ni] = __builtin_amdgcn_mfma_f32_16x16x32_bf16(af[mi][kk], bfr[ni][kk], acc[mi][ni], 0, 0, 0);
    __builtin_amdgcn_s_setprio(0);
    __builtin_amdgcn_sched_barrier(0);
    __builtin_amdgcn_s_barrier();

    // ---- phase B: mh=1 ----
    #pragma unroll
    for (int mi = 0; mi < 4; ++mi) {
      const int row = wm * 128 + 64 + mi * 16 + l15;
      #pragma unroll
      for (int kk = 0; kk < 2; ++kk)
        af[mi][kk] = *(const bf16x8*)(cs + row * 128 + (((kk * 4 + lg) ^ (row & 7)) << 4));
    }
    stage_half(Ab, K, kn2, cs, 0, tid);          // S1(t+2): A-lo,B-lo,B-hi
    stage_half(Bb, K, kn2, cs + 32768, 0, tid);
    stage_half(Bb, K, kn2, cs + 32768, 1, tid);
    __builtin_amdgcn_sched_barrier(0);
    __builtin_amdgcn_s_setprio(1);
    #pragma unroll
    for (int kk = 0; kk < 2; ++kk)
      #pragma unroll
      for (int ni = 0; ni < 4; ++ni)
        #pragma unroll
        for (int mi = 0; mi < 4; ++mi)
          acc[4 + mi][ni] = __builtin_amdgcn_mfma_f32_16x16x32_bf16(af[mi][kk], bfr[ni][kk], acc[4 + mi][ni], 0, 0, 0);
    __builtin_amdgcn_s_setprio(0);
    __builtin_amdgcn_sched_barrier(0);
  }

  // ---- epilogue ----
  if constexpr (EPI == 3) {
    __syncthreads();                      // drain DMA; repurpose smem
    float* pb = (float*)smem;             // [256][4][2]
    #pragma unroll
    for (int m8 = 0; m8 < 8; ++m8) {
      const int grow = bm * 256 + wm * 128 + m8 * 16 + lg * 4;
      float rm[4];
      #pragma unroll
      for (int r = 0; r < 4; ++r) rm[r] = -1e30f;
      #pragma unroll
      for (int ni = 0; ni < 4; ++ni) {
        const int gcol = bn * 256 + wn * 64 + ni * 16 + l15;
        const bool ok = gcol < Nout;
        const float bb = ok ? bias[gcol] : 0.0f;
        #pragma unroll
        for (int r = 0; r < 4; ++r) {
          const float v = ok ? (acc[m8][ni][r] + bb) : -1e30f;
          acc[m8][ni][r] = v;
          if (ok) of[(size_t)(grow + r) * Nout + gcol] = v;
          rm[r] = fmaxf(rm[r], v);
        }
      }
      #pragma unroll
      for (int r = 0; r < 4; ++r) {
        float m = rm[r];
        #pragma unroll
        for (int off = 1; off < 16; off <<= 1) m = fmaxf(m, __shfl_xor(m, off));
        float s = 0.f;
        #pragma unroll
        for (int ni = 0; ni < 4; ++ni) s += __expf(acc[m8][ni][r] - m);
        #pragma unroll
        for (int off = 1; off < 16; off <<= 1) s += __shfl_xor(s, off);
        if (l15 == 0) {
          const int lrow = wm * 128 + m8 * 16 + lg * 4 + r;
          pb[(lrow * 4 + wn) * 2] = m;
          pb[(lrow * 4 + wn) * 2 + 1] = s;
        }
      }
    }
    __syncthreads();
    if (tid < 256) {
      float m = -1e30f, s = 0.f;
      #pragma unroll
      for (int q = 0; q < 4; ++q) {
        const float m2 = pb[(tid * 4 + q) * 2];
        const float s2 = pb[(tid * 4 + q) * 2 + 1];
        const float M = fmaxf(m, m2);
        s = s * __expf(m - M) + s2 * __expf(m2 - M);
        m = M;
      }
      const size_t grow = (size_t)(bm * 256 + tid);
      pm[grow * ntile + bn] = m;
      ps[grow * ntile + bn] = s;
    }
  } else {
    #pragma unroll
    for (int m8 = 0; m8 < 8; ++m8) {
      const int grow = bm * 256 + wm * 128 + m8 * 16 + lg * 4;
      #pragma unroll
      for (int ni = 0; ni < 4; ++ni) {
        const int gcol = bn * 256 + wn * 64 + ni * 16 + l15;
        #pragma unroll
        for (int r = 0; r < 4; ++r) {
          const float a = acc[m8][ni][r];
          if constexpr (EPI == 0) {
            obf[(size_t)(gcol >> 10) * 4194304 + (size_t)(grow + r) * 1024 + (gcol & 1023)] = f2bf(a);
          } else {
            const float gv = a + bias[gcol];
            obf[(size_t)(grow + r) * Nout + gcol] = f2bf(0.5f * gv * (1.0f + erff(gv * 0.70710678118f)));
          }
        }
      }
    }
  }
}

// ---------------- small-M GEMM: 64x128 tile, residual += ----------------
__global__ __launch_bounds__(256) void k_gemm_s(
    const u16* __restrict__ A, const u16* __restrict__ Bt,
    const float* __restrict__ bias, float* __restrict__ of, int K, int Nout) {
  __shared__ u16 Al[64 * 32];
  __shared__ u16 Bl[128 * 32];
  const int tid = threadIdx.x;
  const int lane = tid & 63;
  const int wid = tid >> 6;
  const int bm = blockIdx.x;
  const int bn = blockIdx.y;
  const int wr = wid >> 1, wc = wid & 1;
  const int l15 = lane & 15, lg = lane >> 4;

  f32x4 acc[2][4];
  #pragma unroll
  for (int i = 0; i < 2; ++i)
    #pragma unroll
    for (int j = 0; j < 4; ++j) { f32x4 z = {0.f,0.f,0.f,0.f}; acc[i][j] = z; }

  const u16* Ab = A + (size_t)(bm * 64) * K;
  const u16* Bb = Bt + (size_t)(bn * 128) * K;
  const int srow = tid >> 2;
  const int scol = (tid & 3) * 8;
  char* AlB = (char*)Al;
  char* BlB = (char*)Bl;

  for (int kt = 0; kt < K; kt += 32) {
    gload16(Ab + (size_t)srow * K + kt + scol,        AlB + tid * 16);
    gload16(Bb + (size_t)srow * K + kt + scol,        BlB + tid * 16);
    gload16(Bb + (size_t)(srow + 64) * K + kt + scol, BlB + 4096 + tid * 16);
    __syncthreads();

    bf16x8 af[2], bf[4];
    #pragma unroll
    for (int mi = 0; mi < 2; ++mi)
      af[mi] = *(const bf16x8*)(Al + (wr * 32 + mi * 16 + l15) * 32 + lg * 8);
    #pragma unroll
    for (int ni = 0; ni < 4; ++ni)
      bf[ni] = *(const bf16x8*)(Bl + (wc * 64 + ni * 16 + l15) * 32 + lg * 8);
    #pragma unroll
    for (int ni = 0; ni < 4; ++ni)
      #pragma unroll
      for (int mi = 0; mi < 2; ++mi)
        acc[mi][ni] = __builtin_amdgcn_mfma_f32_16x16x32_bf16(af[mi], bf[ni], acc[mi][ni], 0, 0, 0);
    __syncthreads();
  }

  #pragma unroll
  for (int mi = 0; mi < 2; ++mi) {
    const int grow = bm * 64 + wr * 32 + mi * 16 + lg * 4;
    #pragma unroll
    for (int ni = 0; ni < 4; ++ni) {
      const int gcol = bn * 128 + wc * 64 + ni * 16 + l15;
      #pragma unroll
      for (int r = 0; r < 4; ++r)
        of[(size_t)(grow + r) * Nout + gcol] += acc[mi][ni][r] + bias[gcol];
    }
  }
}

// ---------------- legacy head GEMM (f32 B, used only if d_ws too small) ----------------
__global__ __launch_bounds__(256) void k_gemm_legacy3(
    const u16* __restrict__ A, const float* __restrict__ B0,
    const float* __restrict__ bias, float* __restrict__ of,
    int M, int N, int K) {
  __shared__ u16 Al[128 * 32];
  __shared__ u16 Bl[32 * 128];
  const int tid = threadIdx.x;
  const int lane = tid & 63;
  const int wid = tid >> 6;
  const int bn = blockIdx.x;
  const int bm = blockIdx.y;
  const int wr = wid >> 1, wc = wid & 1;
  const int l15 = lane & 15, lg = lane >> 4;
  f32x4 acc[4][4];
  #pragma unroll
  for (int i = 0; i < 4; ++i)
    #pragma unroll
    for (int j = 0; j < 4; ++j) { f32x4 z = {0.f,0.f,0.f,0.f}; acc[i][j] = z; }
  const u16* Abase = A + (size_t)(bm * 128) * K;
  const int ar0 = tid >> 2;
  const int ac0 = (tid & 3) * 8;
  const int brow = tid >> 3;
  const int bc0 = (tid & 7) * 16;
  for (int kt = 0; kt < K; kt += 32) {
    *(u16x8*)(Al + ar0 * 32 + ac0) =
        *(const u16x8*)(Abase + (size_t)ar0 * K + kt + ac0);
    *(u16x8*)(Al + (ar0 + 64) * 32 + ac0) =
        *(const u16x8*)(Abase + (size_t)(ar0 + 64) * K + kt + ac0);
    {
      const float* bsrc = B0 + (size_t)(kt + brow) * N + bn * 128 + bc0;
      alignas(16) u16 tmp[16];
      const int colbase = bn * 128 + bc0;
      #pragma unroll
      for (int q = 0; q < 16; ++q)
        tmp[q] = f2bf((colbase + q < N) ? bsrc[q] : 0.0f);
      *(u16x8*)(Bl + brow * 128 + bc0) = *(const u16x8*)tmp;
      *(u16x8*)(Bl + brow * 128 + bc0 + 8) = *(const u16x8*)(tmp + 8);
    }
    __syncthreads();
    bf16x8 af[4];
    #pragma unroll
    for (int mi = 0; mi < 4; ++mi)
      af[mi] = *(const bf16x8*)(Al + (wr * 64 + mi * 16 + l15) * 32 + lg * 8);
    #pragma unroll
    for (int ni = 0; ni < 4; ++ni) {
      u16x8 tv;
      #pragma unroll
      for (int i = 0; i < 8; ++i)
        tv[i] = Bl[(lg * 8 + i) * 128 + wc * 64 + ni * 16 + l15];
      const bf16x8 bfr = __builtin_bit_cast(bf16x8, tv);
      #pragma unroll
      for (int mi = 0; mi < 4; ++mi)
        acc[mi][ni] = __builtin_amdgcn_mfma_f32_16x16x32_bf16(af[mi], bfr, acc[mi][ni], 0, 0, 0);
    }
    __syncthreads();
  }
  #pragma unroll
  for (int mi = 0; mi < 4; ++mi) {
    const int grow = bm * 128 + wr * 64 + mi * 16 + lg * 4;
    #pragma unroll
    for (int ni = 0; ni < 4; ++ni) {
      const int gcol = bn * 128 + wc * 64 + ni * 16 + l15;
      #pragma unroll
      for (int r = 0; r < 4; ++r)
        if (gcol < N) of[(size_t)(grow + r) * N + gcol] = acc[mi][ni][r] + bias[gcol];
    }
  }
}

// ---------------- causal flash attention (XOR-swizzled LDS) ----------------
__global__ __launch_bounds__(256, 2) void k_attn(
    const u16* __restrict__ qg, const u16* __restrict__ kg,
    const u16* __restrict__ vg, u16* __restrict__ og) {
  __shared__ u16 Kl[64 * 64];
  __shared__ u16 Vt[64 * 64];
  __shared__ u16 Pl[4][16 * 64];
  const int tid = threadIdx.x;
  const int lane = tid & 63;
  const int w = tid >> 6;
  const int qt = blockIdx.x;
  const int bh = blockIdx.y;
  const int b = bh >> 4, h = bh & 15;
  const int l15 = lane & 15, lg = lane >> 4;
  char* KlB = (char*)Kl;
  char* VtB = (char*)Vt;
  char* PlB = (char*)(Pl[w]);

  const size_t qrow0 = (size_t)b * cT + qt * 64 + w * 16;
  bf16x8 aq[2];
  #pragma unroll
  for (int c = 0; c < 2; ++c)
    aq[c] = *(const bf16x8*)(qg + (qrow0 + l15) * cE + h * 64 + c * 32 + lg * 8);

  f32x4 acco[4];
  #pragma unroll
  for (int j = 0; j < 4; ++j) { f32x4 z = {0.f,0.f,0.f,0.f}; acco[j] = z; }
  float mrun[4], lrun[4];
  #pragma unroll
  for (int r = 0; r < 4; ++r) { mrun[r] = -1e30f; lrun[r] = 0.f; }

  for (int kt = 0; kt <= qt; ++kt) {
    const size_t krow0 = (size_t)b * cT + kt * 64;
    #pragma unroll
    for (int u = 0; u < 2; ++u) {
      const int un = tid + u * 256;
      const int rr = un >> 3, c8 = (un & 7) * 8;
      *(u16x8*)(KlB + rr * 128 + swzoff(rr, c8 >> 3)) =
          *(const u16x8*)(kg + (krow0 + rr) * cE + h * 64 + c8);
      const u16x8 vv = *(const u16x8*)(vg + (krow0 + rr) * cE + h * 64 + c8);
      #pragma unroll
      for (int i = 0; i < 8; ++i)
        *(u16*)(VtB + (c8 + i) * 128 + swzoff(c8 + i, rr >> 3) + (rr & 7) * 2) = vv[i];
    }
    __syncthreads();

    f32x4 s[4];
    #pragma unroll
    for (int j = 0; j < 4; ++j) { f32x4 z = {0.f,0.f,0.f,0.f}; s[j] = z; }
    #pragma unroll
    for (int c = 0; c < 2; ++c) {
      #pragma unroll
      for (int j = 0; j < 4; ++j) {
        const int n = j * 16 + l15;
        const bf16x8 kb2 = *(const bf16x8*)(KlB + n * 128 + swzoff(n, c * 4 + lg));
        s[j] = __builtin_amdgcn_mfma_f32_16x16x32_bf16(aq[c], kb2, s[j], 0, 0, 0);
      }
    }

    float sv[4][4];
    const bool diag = (kt == qt);
    #pragma unroll
    for (int j = 0; j < 4; ++j)
      #pragma unroll
      for (int r = 0; r < 4; ++r) {
        float xs = s[j][r] * 0.125f;
        if (diag && (j * 16 + l15) > (w * 16 + lg * 4 + r)) xs = -1e30f;
        sv[j][r] = xs;
      }

    float corr[4];
    #pragma unroll
    for (int r = 0; r < 4; ++r) {
      float mx = fmaxf(fmaxf(sv[0][r], sv[1][r]), fmaxf(sv[2][r], sv[3][r]));
      #pragma unroll
      for (int off = 1; off < 16; off <<= 1) mx = fmaxf(mx, __shfl_xor(mx, off));
      const float mnew = fmaxf(mrun[r], mx);
      corr[r] = __expf(mrun[r] - mnew);
      float rs = 0.f;
      #pragma unroll
      for (int j = 0; j < 4; ++j) {
        const float p = __expf(sv[j][r] - mnew);
        sv[j][r] = p;
        rs += p;
      }
      #pragma unroll
      for (int off = 1; off < 16; off <<= 1) rs += __shfl_xor(rs, off);
      lrun[r] = lrun[r] * corr[r] + rs;
      mrun[r] = mnew;
    }

    #pragma unroll
    for (int j = 0; j < 4; ++j)
      #pragma unroll
      for (int r = 0; r < 4; ++r) {
        const int qr = lg * 4 + r, kc = j * 16 + l15;
        *(u16*)(PlB + qr * 128 + swzoff(qr, kc >> 3) + (kc & 7) * 2) = f2bf(sv[j][r]);
        acco[j][r] *= corr[r];
      }

    #pragma unroll
    for (int c = 0; c < 2; ++c) {
      const bf16x8 pa = *(const bf16x8*)(PlB + l15 * 128 + swzoff(l15, c * 4 + lg));
      #pragma unroll
      for (int j = 0; j < 4; ++j) {
        const int n = j * 16 + l15;
        const bf16x8 vb2 = *(const bf16x8*)(VtB + n * 128 + swzoff(n, c * 4 + lg));
        acco[j] = __builtin_amdgcn_mfma_f32_16x16x32_bf16(pa, vb2, acco[j], 0, 0, 0);
      }
    }
    __syncthreads();
  }

  #pragma unroll
  for (int j = 0; j < 4; ++j)
    #pragma unroll
    for (int r = 0; r < 4; ++r)
      og[(qrow0 + lg * 4 + r) * cE + h * 64 + j * 16 + l15] = f2bf(acco[j][r] / lrun[r]);
}

// ---------------- NLL from per-tile partials ----------------
__global__ __launch_bounds__(256) void k_nll2(const float* __restrict__ pm,
    const float* __restrict__ ps, const float* __restrict__ logits,
    const int* __restrict__ tgt, float* __restrict__ nll, int NT) {
  const int row = blockIdx.x * 4 + (threadIdx.x >> 6);
  const int lane = threadIdx.x & 63;
  float m = -1e30f, s = 0.f;
  for (int i = lane; i < NT; i += 64) {
    const float m2 = pm[(size_t)row * NT + i];
    const float s2 = ps[(size_t)row * NT + i];
    const float M = fmaxf(m, m2);
    s = s * __expf(m - M) + s2 * __expf(m2 - M);
    m = M;
  }
  #pragma unroll
  for (int off = 1; off < 64; off <<= 1) {
    const float m2 = __shfl_xor(m, off);
    const float s2 = __shfl_xor(s, off);
    const float M = fmaxf(m, m2);
    s = s * __expf(m - M) + s2 * __expf(m2 - M);
    m = M;
  }
  if (lane == 0)
    nll[row] = logf(s) + m - logits[(size_t)row * cV + tgt[row]];
}

// ---------------- per-row NLL over V (fallback) ----------------
__global__ __launch_bounds__(256) void k_nll(const float* __restrict__ logits,
    const int* __restrict__ tgt, float* __restrict__ nll) {
  const int row = blockIdx.x;
  const float* lp = logits + (size_t)row * cV;
  const int t = threadIdx.x;
  __shared__ float red[8];
  const int wid = t >> 6, lane = t & 63;
  float mx = -1e30f;
  for (int i = t; i < cV; i += 256) mx = fmaxf(mx, lp[i]);
  #pragma unroll
  for (int off = 32; off; off >>= 1) mx = fmaxf(mx, __shfl_xor(mx, off));
  if (lane == 0) red[wid] = mx;
  __syncthreads();
  mx = fmaxf(fmaxf(red[0], red[1]), fmaxf(red[2], red[3]));
  float s = 0.f;
  for (int i = t; i < cV; i += 256) s += __expf(lp[i] - mx);
  #pragma unroll
  for (int off = 32; off; off >>= 1) s += __shfl_xor(s, off);
  if (lane == 0) red[4 + wid] = s;
  __syncthreads();
  if (t == 0) {
    s = red[4] + red[5] + red[6] + red[7];
    nll[row] = logf(s) + mx - lp[tgt[row]];
  }
}

__global__ __launch_bounds__(256) void k_loss(const float* __restrict__ nll,
    float* __restrict__ out) {
  const int t = threadIdx.x;
  float s = 0.f;
  for (int i = t; i < cBT; i += 256) s += nll[i];
  #pragma unroll
  for (int off = 32; off; off >>= 1) s += __shfl_xor(s, off);
  __shared__ float red[4];
  if ((t & 63) == 0) red[t >> 6] = s;
  __syncthreads();
  if (t == 0) out[0] = (red[0] + red[1] + red[2] + red[3]) * (1.0f / cBT);
}

extern "C" void kernel_launch(void* const* d_in, const int* in_sizes, int n_in,
                              void* d_out, int out_size, void* d_ws, size_t ws_size,
                              hipStream_t stream) {
  const int*   idx  = (const int*)d_in[0];
  const int*   tgt  = (const int*)d_in[1];
  const float* tok  = (const float*)d_in[2];
  const float* pos  = (const float*)d_in[3];
  const float* Wq   = (const float*)d_in[4];
  const float* Wk   = (const float*)d_in[5];
  const float* Wv   = (const float*)d_in[6];
  const float* Wo   = (const float*)d_in[7];
  const float* bo   = (const float*)d_in[8];
  const float* ln1g = (const float*)d_in[9];
  const float* ln1b = (const float*)d_in[10];
  const float* ln2g = (const float*)d_in[11];
  const float* ln2b = (const float*)d_in[12];
  const float* W1   = (const float*)d_in[13];
  const float* b1   = (const float*)d_in[14];
  const float* W2   = (const float*)d_in[15];
  const float* b2   = (const float*)d_in[16];
  const float* lnfg = (const float*)d_in[17];
  const float* lnfb = (const float*)d_in[18];
  const float* Wh   = (const float*)d_in[19];
  const float* bh   = (const float*)d_in[20];

  // --- d_out scratch plan (all dead before head GEMM overwrites d_out) ---
  char* ob = (char*)d_out;
  float* x    = (float*)ob;                          // [BT,E] f32, 16 MB
  u16* hb     = (u16*)(ob + (16u << 20));
  u16* qb     = (u16*)(ob + (24u << 20));            // q/k/v contiguous slabs
  u16* kb     = (u16*)(ob + (32u << 20));
  u16* vb     = (u16*)(ob + (40u << 20));
  u16* abuf   = (u16*)(ob + (48u << 20));
  u16* fbuf   = (u16*)(ob + (56u << 20));            // [BT,FF] bf16 -> ends 88M
  u16* W3T    = (u16*)(ob + (128u << 20));           // 12 x [3][E][E] (72MB) -> 200M
  u16* WoT    = (u16*)(ob + (200u << 20));           // 12 x [E][E]   (24MB) -> 224M
  u16* W1T    = (u16*)(ob + (224u << 20));           // 12 x [FF][E]  (96MB) -> 320M
  u16* W2T    = (u16*)(ob + (320u << 20));           // 12 x [E][FF]  (96MB) -> 416M
  // --- d_ws layout ---
  u16* hf     = (u16*)d_ws;                          // 8.39 MB
  float* nll  = (float*)((char*)d_ws + 8388608);
  u16* WheadT = (u16*)((char*)d_ws + 8404992);       // [cVp][E] bf16 (103.3 MB)
  const size_t whead_end = 8404992u + (size_t)cVp * cE * 2u;   // 111,689,728
  float* pmax = (float*)((char*)d_ws + whead_end);
  float* psum = (float*)((char*)d_ws + whead_end + (size_t)cBT * cNT * 4);
  const size_t ws_need = whead_end + 2u * (size_t)cBT * cNT * 4;
  const bool fast_head = ws_size >= ws_need;

  float* logits = (float*)d_out;
  float* loss = logits + (size_t)cBT * cV;

  const dim3 blk(256);
  const size_t e2 = (size_t)cE * cE, ef = (size_t)cE * cFF;

  // weight conversion (every call)
  k_cvt_t<<<dim3(32, 32, cL), blk, 0, stream>>>(Wq, W3T,          cE, cE, e2, 3 * e2);
  k_cvt_t<<<dim3(32, 32, cL), blk, 0, stream>>>(Wk, W3T + e2,     cE, cE, e2, 3 * e2);
  k_cvt_t<<<dim3(32, 32, cL), blk, 0, stream>>>(Wv, W3T + 2 * e2, cE, cE, e2, 3 * e2);
  k_cvt_t<<<dim3(32, 32, cL), blk, 0, stream>>>(Wo, WoT, cE, cE, e2, e2);
  k_cvt_t<<<dim3(128, 32, cL), blk, 0, stream>>>(W1, W1T, cE, cFF, ef, ef);
  k_cvt_t<<<dim3(32, 128, cL), blk, 0, stream>>>(W2, W2T, cFF, cE, ef, ef);
  if (fast_head)
    k_cvt_t<<<dim3(cVp / 32, 32, 1), blk, 0, stream>>>(Wh, WheadT, cE, cV, 0, 0);

  k_embed<<<dim3(cBT), blk, 0, stream>>>(idx, tok, pos, x);
  for (int l = 0; l < cL; ++l) {
    k_ln<<<dim3(cBT), blk, 0, stream>>>(x, ln1g + l * cE, ln1b + l * cE, hb);
    k_gemm2<0><<<dim3(16, 12), dim3(512), 0, stream>>>(hb, W3T + l * 3 * e2,
        nullptr, qb, nullptr, cE, 3072, 0, nullptr, nullptr);
    k_attn<<<dim3(16, 64), blk, 0, stream>>>(qb, kb, vb, abuf);
    k_gemm_s<<<dim3(64, 8), blk, 0, stream>>>(abuf, WoT + l * e2, bo + l * cE, x, cE, cE);
    k_ln<<<dim3(cBT), blk, 0, stream>>>(x, ln2g + l * cE, ln2b + l * cE, hb);
    k_gemm2<2><<<dim3(16, 16), dim3(512), 0, stream>>>(hb, W1T + l * ef,
        b1 + l * cFF, fbuf, nullptr, cE, cFF, 0, nullptr, nullptr);
    k_gemm_s<<<dim3(64, 8), blk, 0, stream>>>(fbuf, W2T + l * ef, b2 + l * cE, x, cFF, cE);
  }
  k_ln<<<dim3(cBT), blk, 0, stream>>>(x, lnfg, lnfb, hf);
  if (fast_head) {
    k_gemm2<3><<<dim3(16, cNT), dim3(512), 0, stream>>>(hf, WheadT, bh,
        nullptr, logits, cE, cV, cNT, pmax, psum);
    k_nll2<<<dim3(cBT / 4), blk, 0, stream>>>(pmax, psum, logits, tgt, nll, cNT);
  } else {
    k_gemm_legacy3<<<dim3(393, 32), blk, 0, stream>>>(hf, Wh, bh, logits, cBT, cV, cE);
    k_nll<<<dim3(cBT), blk, 0, stream>>>(logits, tgt, nll);
  }
  k_loss<<<dim3(1), blk, 0, stream>>>(nll, loss);
}

// Round 5
// 4662.707 us; speedup vs baseline: 1.8548x; 1.0793x over previous
//
#include <hip/hip_runtime.h>
#include <cstdint>
#include <cstddef>

typedef unsigned short u16;
typedef __bf16 bf16x8 __attribute__((ext_vector_type(8)));
typedef float f32x4 __attribute__((ext_vector_type(4)));
typedef unsigned short u16x8 __attribute__((ext_vector_type(8)));
typedef unsigned short u16x4 __attribute__((ext_vector_type(4)));

constexpr int cV  = 50257;
constexpr int cVp = 50432;   // padded to 256
constexpr int cNT = cVp / 256;  // 197 head n-tiles
constexpr int cT  = 1024;
constexpr int cE  = 1024;
constexpr int cL  = 12;
constexpr int cFF = 4096;
constexpr int cBT = 4096;    // B*T

__device__ __forceinline__ u16 f2bf(float f) {
  union { float f; unsigned u; } x; x.f = f;
  unsigned r = x.u + 0x7fffu + ((x.u >> 16) & 1u);   // RNE
  return (u16)(r >> 16);
}

// async global->LDS, 16B per lane. dest must be linear in lane order.
__device__ __forceinline__ void gload16(const void* g, void* l) {
  __builtin_amdgcn_global_load_lds(
      (const __attribute__((address_space(1))) void*)g,
      (__attribute__((address_space(3))) void*)l, 16, 0, 0);
}

// XOR swizzle for 128B-wide LDS rows (attn): permute 16B chunks within row.
__device__ __forceinline__ int swzoff(int row, int chunk) {
  return ((chunk ^ (row & 7) ^ ((row >> 3) & 7)) << 4);
}

// bijective XCD-chunk swizzle for grids with nwg % 8 == 0
__device__ __forceinline__ int xcd_swz(int id, int nwg) {
  if ((nwg & 7) == 0) { const int q = nwg >> 3; return (id & 7) * q + (id >> 3); }
  return id;
}

// ---------------- embedding ----------------
__global__ __launch_bounds__(256) void k_embed(const int* __restrict__ idx,
    const float* __restrict__ tok, const float* __restrict__ pos,
    float* __restrict__ x) {
  const int row = blockIdx.x;
  const int t = row & (cT - 1);
  const int tk = idx[row];
  const float4* tv = (const float4*)(tok + (size_t)tk * cE);
  const float4* pv = (const float4*)(pos + (size_t)t * cE);
  float4* xv = (float4*)(x + (size_t)row * cE);
  const int i = threadIdx.x;
  float4 a = tv[i];
  float4 p = pv[i];
  a.x += p.x; a.y += p.y; a.z += p.z; a.w += p.w;
  xv[i] = a;
}

// ---------------- layernorm (f32 in -> bf16 out) ----------------
__global__ __launch_bounds__(256) void k_ln(const float* __restrict__ x,
    const float* __restrict__ gw, const float* __restrict__ bw,
    u16* __restrict__ out) {
  const int row = blockIdx.x;
  const int t = threadIdx.x;
  const float4 v = ((const float4*)(x + (size_t)row * cE))[t];
  float s1 = v.x + v.y + v.z + v.w;
  float s2 = v.x * v.x + v.y * v.y + v.z * v.z + v.w * v.w;
  #pragma unroll
  for (int off = 32; off; off >>= 1) {
    s1 += __shfl_xor(s1, off);
    s2 += __shfl_xor(s2, off);
  }
  __shared__ float red[8];
  const int wid = t >> 6;
  if ((t & 63) == 0) { red[wid] = s1; red[4 + wid] = s2; }
  __syncthreads();
  s1 = red[0] + red[1] + red[2] + red[3];
  s2 = red[4] + red[5] + red[6] + red[7];
  const float mean = s1 * (1.0f / cE);
  const float var = s2 * (1.0f / cE) - mean * mean;
  const float rs = rsqrtf(var + 1e-5f);
  const float4 g4 = ((const float4*)gw)[t];
  const float4 b4 = ((const float4*)bw)[t];
  u16x4 o;
  o[0] = f2bf((v.x - mean) * rs * g4.x + b4.x);
  o[1] = f2bf((v.y - mean) * rs * g4.y + b4.y);
  o[2] = f2bf((v.z - mean) * rs * g4.z + b4.z);
  o[3] = f2bf((v.w - mean) * rs * g4.w + b4.w);
  *(u16x4*)(out + (size_t)row * cE + t * 4) = o;
}

// ---------------- weight convert+transpose: f32[K][N] -> bf16[N][K] ----------------
__global__ __launch_bounds__(256) void k_cvt_t(const float* __restrict__ src,
    u16* __restrict__ dst, int K, int Nsrc, size_t sstride, size_t dstride) {
  __shared__ float tile[32][33];
  const float* s = src + blockIdx.z * sstride;
  u16* d = dst + blockIdx.z * dstride;
  const int n0 = blockIdx.x * 32, k0 = blockIdx.y * 32;
  const int t = threadIdx.x;
  const int c = t & 31, r0 = t >> 5;
  #pragma unroll
  for (int i = 0; i < 4; ++i) {
    const int kl = r0 + i * 8;
    const int n = n0 + c;
    tile[kl][c] = (n < Nsrc) ? s[(size_t)(k0 + kl) * Nsrc + n] : 0.0f;
  }
  __syncthreads();
  #pragma unroll
  for (int i = 0; i < 4; ++i) {
    const int nl = r0 + i * 8;
    d[(size_t)(n0 + nl) * K + k0 + c] = f2bf(tile[c][nl]);
  }
}

// ============== 256x256 deep-pipelined GEMM, 4 phases/K-tile ==============
// C[M,Nout] = A[M][K](bf16) @ Bt[Npad][K](bf16)^T. BK=64, 512 thr = 8 waves
// (2M x 4N), per-wave 128x64 out. LDS 128KB: 2 bufs x (A 32K + B 32K);
// rows = 8x16B chunks, chunk XOR-swizzled by (row&7), global src pre-swz.
// Per tile: vmcnt(6)+bar | P1: ds af-lo+bfr01, issue S2(t+1), 16 MFMA | bar
// | P2: ds bfr23, 16 MFMA | bar | P3: ds af-hi, issue S1(t+2), 16 MFMA |
// bar | P4: 16 MFMA.  All ds_reads consumed in-phase (DMA-overwrite safe).
__device__ __forceinline__ void stage_half(const u16* __restrict__ Mb, int K,
    int kt, char* lds, int half, int tid) {
  #pragma unroll
  for (int p = 0; p < 2; ++p) {
    const int L = half * 1024 + p * 512 + tid;
    const int row = L >> 3, cc = L & 7;
    gload16(Mb + (size_t)row * K + kt + ((cc ^ (row & 7)) << 3),
            lds + (size_t)L * 16);
  }
}

template<int EPI>
__global__ __launch_bounds__(512) void k_gemm2(
    const u16* __restrict__ A, const u16* __restrict__ Bt,
    const float* __restrict__ bias, u16* __restrict__ obf,
    float* __restrict__ of, int K, int Nout, int ntile, int mt,
    float* __restrict__ pm, float* __restrict__ ps) {
  __shared__ __align__(16) char smem[131072];
  const int tid = threadIdx.x;
  const int lane = tid & 63;
  const int wid = tid >> 6;
  const int wg = xcd_swz((int)blockIdx.x, (int)gridDim.x);
  const int bm = wg % mt;
  const int bn = wg / mt;
  const int wm = wid >> 2, wn = wid & 3;
  const int l15 = lane & 15, lg = lane >> 4;

  f32x4 acc[8][4];
  #pragma unroll
  for (int i = 0; i < 8; ++i)
    #pragma unroll
    for (int j = 0; j < 4; ++j) { f32x4 z = {0.f,0.f,0.f,0.f}; acc[i][j] = z; }

  const u16* Ab = A + (size_t)(bm * 256) * K;
  const u16* Bb = Bt + (size_t)(bn * 256) * K;
  const int nt = K >> 6;

  // prologue: S1(0)->buf0, S2(0)->buf0, S1(1)->buf1  (14 loads/thread)
  {
    char* s0 = smem;
    char* s1 = smem + 65536;
    stage_half(Ab, K, 0, s0, 0, tid);
    stage_half(Bb, K, 0, s0 + 32768, 0, tid);
    stage_half(Bb, K, 0, s0 + 32768, 1, tid);
    stage_half(Ab, K, 0, s0, 1, tid);
    const int k1 = (nt > 1) ? 64 : 0;
    stage_half(Ab, K, k1, s1, 0, tid);
    stage_half(Bb, K, k1, s1 + 32768, 0, tid);
    stage_half(Bb, K, k1, s1 + 32768, 1, tid);
  }

  bf16x8 af[4][2], bfr[4][2];
  for (int t = 0; t < nt; ++t) {
    char* cs = smem + ((t & 1) << 16);
    char* co = smem + (((t & 1) ^ 1) << 16);
    const char* csB = cs + 32768;
    const int kn1 = (t + 1 < nt ? t + 1 : nt - 1) << 6;
    const int kn2 = (t + 2 < nt ? t + 2 : nt - 1) << 6;

    asm volatile("s_waitcnt vmcnt(6)" ::: "memory");
    __builtin_amdgcn_s_barrier();

    // ---- P1: af-lo + bfr[0..1]; issue S2(t+1); MFMA m0-3 x n0-1 ----
    #pragma unroll
    for (int mi = 0; mi < 4; ++mi) {
      const int row = wm * 128 + mi * 16 + l15;
      #pragma unroll
      for (int kk = 0; kk < 2; ++kk)
        af[mi][kk] = *(const bf16x8*)(cs + row * 128 + (((kk * 4 + lg) ^ (row & 7)) << 4));
    }
    #pragma unroll
    for (int ni = 0; ni < 2; ++ni) {
      const int rowB = wn * 64 + ni * 16 + l15;
      #pragma unroll
      for (int kk = 0; kk < 2; ++kk)
        bfr[ni][kk] = *(const bf16x8*)(csB + rowB * 128 + (((kk * 4 + lg) ^ (rowB & 7)) << 4));
    }
    stage_half(Ab, K, kn1, co, 1, tid);          // S2(t+1): A-hi
    __builtin_amdgcn_sched_barrier(0);
    __builtin_amdgcn_s_setprio(1);
    #pragma unroll
    for (int kk = 0; kk < 2; ++kk)
      #pragma unroll
      for (int ni = 0; ni < 2; ++ni)
        #pragma unroll
        for (int mi = 0; mi < 4; ++mi)
          acc[mi][ni] = __builtin_amdgcn_mfma_f32_16x16x32_bf16(af[mi][kk], bfr[ni][kk], acc[mi][ni], 0, 0, 0);
    __builtin_amdgcn_s_setprio(0);
    __builtin_amdgcn_sched_barrier(0);
    __builtin_amdgcn_s_barrier();

    // ---- P2: bfr[2..3]; MFMA m0-3 x n2-3 ----
    #pragma unroll
    for (int ni = 2; ni < 4; ++ni) {
      const int rowB = wn * 64 + ni * 16 + l15;
      #pragma unroll
      for (int kk = 0; kk < 2; ++kk)
        bfr[ni][kk] = *(const bf16x8*)(csB + rowB * 128 + (((kk * 4 + lg) ^ (rowB & 7)) << 4));
    }
    __builtin_amdgcn_sched_barrier(0);
    __builtin_amdgcn_s_setprio(1);
    #pragma unroll
    for (int kk = 0; kk < 2; ++kk)
      #pragma unroll
      for (int ni = 2; ni < 4; ++ni)
        #pragma unroll
        for (int mi = 0; mi < 4; ++mi)
          acc[mi][ni] = __builtin_amdgcn_mfma_f32_16x16x32_bf16(af[mi][kk], bfr[ni][kk], acc[mi][ni], 0, 0, 0);
    __builtin_amdgcn_s_setprio(0);
    __builtin_amdgcn_sched_barrier(0);
    __builtin_amdgcn_s_barrier();

    // ---- P3: af-hi; issue S1(t+2); MFMA m4-7 x n0-1 ----
    #pragma unroll
    for (int mi = 0; mi < 4; ++mi) {
      const int row = wm * 128 + 64 + mi * 16 + l15;
      #pragma unroll
      for (int kk = 0; kk < 2; ++kk)
        af[mi][kk] = *(const bf16x8*)(cs + row * 128 + (((kk * 4 + lg) ^ (row & 7)) << 4));
    }
    stage_half(Ab, K, kn2, cs, 0, tid);          // S1(t+2): A-lo, B-lo, B-hi
    stage_half(Bb, K, kn2, cs + 32768, 0, tid);
    stage_half(Bb, K, kn2, cs + 32768, 1, tid);
    __builtin_amdgcn_sched_barrier(0);
    __builtin_amdgcn_s_setprio(1);
    #pragma unroll
    for (int kk = 0; kk < 2; ++kk)
      #pragma unroll
      for (int ni = 0; ni < 2; ++ni)
        #pragma unroll
        for (int mi = 0; mi < 4; ++mi)
          acc[4 + mi][ni] = __builtin_amdgcn_mfma_f32_16x16x32_bf16(af[mi][kk], bfr[ni][kk], acc[4 + mi][ni], 0, 0, 0);
    __builtin_amdgcn_s_setprio(0);
    __builtin_amdgcn_sched_barrier(0);
    __builtin_amdgcn_s_barrier();

    // ---- P4: MFMA m4-7 x n2-3 ----
    __builtin_amdgcn_s_setprio(1);
    #pragma unroll
    for (int kk = 0; kk < 2; ++kk)
      #pragma unroll
      for (int ni = 2; ni < 4; ++ni)
        #pragma unroll
        for (int mi = 0; mi < 4; ++mi)
          acc[4 + mi][ni] = __builtin_amdgcn_mfma_f32_16x16x32_bf16(af[mi][kk], bfr[ni][kk], acc[4 + mi][ni], 0, 0, 0);
    __builtin_amdgcn_s_setprio(0);
    __builtin_amdgcn_sched_barrier(0);
  }
  asm volatile("s_waitcnt vmcnt(0)" ::: "memory");

  // ---- epilogue ----
  if constexpr (EPI == 3) {
    __syncthreads();                      // repurpose smem
    float* pb = (float*)smem;             // [256][4][2]
    #pragma unroll
    for (int m8 = 0; m8 < 8; ++m8) {
      const int grow = bm * 256 + wm * 128 + m8 * 16 + lg * 4;
      float rm[4];
      #pragma unroll
      for (int r = 0; r < 4; ++r) rm[r] = -1e30f;
      #pragma unroll
      for (int ni = 0; ni < 4; ++ni) {
        const int gcol = bn * 256 + wn * 64 + ni * 16 + l15;
        const bool ok = gcol < Nout;
        const float bb = ok ? bias[gcol] : 0.0f;
        #pragma unroll
        for (int r = 0; r < 4; ++r) {
          const float v = ok ? (acc[m8][ni][r] + bb) : -1e30f;
          acc[m8][ni][r] = v;
          if (ok) of[(size_t)(grow + r) * Nout + gcol] = v;
          rm[r] = fmaxf(rm[r], v);
        }
      }
      #pragma unroll
      for (int r = 0; r < 4; ++r) {
        float m = rm[r];
        #pragma unroll
        for (int off = 1; off < 16; off <<= 1) m = fmaxf(m, __shfl_xor(m, off));
        float s = 0.f;
        #pragma unroll
        for (int ni = 0; ni < 4; ++ni) s += __expf(acc[m8][ni][r] - m);
        #pragma unroll
        for (int off = 1; off < 16; off <<= 1) s += __shfl_xor(s, off);
        if (l15 == 0) {
          const int lrow = wm * 128 + m8 * 16 + lg * 4 + r;
          pb[(lrow * 4 + wn) * 2] = m;
          pb[(lrow * 4 + wn) * 2 + 1] = s;
        }
      }
    }
    __syncthreads();
    if (tid < 256) {
      float m = -1e30f, s = 0.f;
      #pragma unroll
      for (int q = 0; q < 4; ++q) {
        const float m2 = pb[(tid * 4 + q) * 2];
        const float s2 = pb[(tid * 4 + q) * 2 + 1];
        const float M = fmaxf(m, m2);
        s = s * __expf(m - M) + s2 * __expf(m2 - M);
        m = M;
      }
      const size_t grow = (size_t)(bm * 256 + tid);
      pm[grow * ntile + bn] = m;
      ps[grow * ntile + bn] = s;
    }
  } else {
    #pragma unroll
    for (int m8 = 0; m8 < 8; ++m8) {
      const int grow = bm * 256 + wm * 128 + m8 * 16 + lg * 4;
      #pragma unroll
      for (int ni = 0; ni < 4; ++ni) {
        const int gcol = bn * 256 + wn * 64 + ni * 16 + l15;
        #pragma unroll
        for (int r = 0; r < 4; ++r) {
          const float a = acc[m8][ni][r];
          if constexpr (EPI == 0) {
            obf[(size_t)(gcol >> 10) * 4194304 + (size_t)(grow + r) * 1024 + (gcol & 1023)] = f2bf(a);
          } else {
            const float gv = a + bias[gcol];
            obf[(size_t)(grow + r) * Nout + gcol] = f2bf(0.5f * gv * (1.0f + erff(gv * 0.70710678118f)));
          }
        }
      }
    }
  }
}

// ------- small-M pipelined GEMM: 64x128 tile, BK=64, residual += -------
// 2 bufs x 24KB (A 8K + B 16K) = 48KB, 2 blocks/CU. Per tile: vmcnt(6)+bar
// | P1: ds all (12), MFMA kk=0, lgkmcnt(0) | bar | P2: stage(t+2), MFMA kk=1.
__global__ __launch_bounds__(256) void k_gemm_s(
    const u16* __restrict__ A, const u16* __restrict__ Bt,
    const float* __restrict__ bias, float* __restrict__ of,
    int K, int Nout, int mt) {
  __shared__ __align__(16) char smem[49152];
  const int tid = threadIdx.x;
  const int lane = tid & 63;
  const int wid = tid >> 6;
  const int wg = xcd_swz((int)blockIdx.x, (int)gridDim.x);
  const int bm = wg % mt;
  const int bn = wg / mt;
  const int wr = wid >> 1, wc = wid & 1;
  const int l15 = lane & 15, lg = lane >> 4;

  f32x4 acc[2][4];
  #pragma unroll
  for (int i = 0; i < 2; ++i)
    #pragma unroll
    for (int j = 0; j < 4; ++j) { f32x4 z = {0.f,0.f,0.f,0.f}; acc[i][j] = z; }

  const u16* Ab = A + (size_t)(bm * 64) * K;
  const u16* Bb = Bt + (size_t)(bn * 128) * K;
  const int nt = K >> 6;

  auto stage = [&](int t, char* buf) {
    const int kt = (t < nt ? t : nt - 1) << 6;
    #pragma unroll
    for (int p = 0; p < 2; ++p) {
      const int L = p * 256 + tid;
      const int row = L >> 3, cc = L & 7;
      gload16(Ab + (size_t)row * K + kt + ((cc ^ (row & 7)) << 3), buf + L * 16);
    }
    #pragma unroll
    for (int p = 0; p < 4; ++p) {
      const int L = p * 256 + tid;
      const int row = L >> 3, cc = L & 7;
      gload16(Bb + (size_t)row * K + kt + ((cc ^ (row & 7)) << 3), buf + 8192 + L * 16);
    }
  };
  stage(0, smem);
  stage(1, smem + 24576);

  for (int t = 0; t < nt; ++t) {
    char* cs = smem + ((t & 1) ? 24576 : 0);
    const char* csB = cs + 8192;
    asm volatile("s_waitcnt vmcnt(6)" ::: "memory");
    __builtin_amdgcn_s_barrier();

    bf16x8 af[2][2], bfr[4][2];
    #pragma unroll
    for (int mi = 0; mi < 2; ++mi) {
      const int row = wr * 32 + mi * 16 + l15;
      #pragma unroll
      for (int kk = 0; kk < 2; ++kk)
        af[mi][kk] = *(const bf16x8*)(cs + row * 128 + (((kk * 4 + lg) ^ (row & 7)) << 4));
    }
    #pragma unroll
    for (int ni = 0; ni < 4; ++ni) {
      const int row = wc * 64 + ni * 16 + l15;
      #pragma unroll
      for (int kk = 0; kk < 2; ++kk)
        bfr[ni][kk] = *(const bf16x8*)(csB + row * 128 + (((kk * 4 + lg) ^ (row & 7)) << 4));
    }
    __builtin_amdgcn_sched_barrier(0);
    __builtin_amdgcn_s_setprio(1);
    #pragma unroll
    for (int ni = 0; ni < 4; ++ni)
      #pragma unroll
      for (int mi = 0; mi < 2; ++mi)
        acc[mi][ni] = __builtin_amdgcn_mfma_f32_16x16x32_bf16(af[mi][0], bfr[ni][0], acc[mi][ni], 0, 0, 0);
    __builtin_amdgcn_s_setprio(0);
    __builtin_amdgcn_sched_barrier(0);
    asm volatile("s_waitcnt lgkmcnt(0)" ::: "memory");   // kk=1 reads landed
    __builtin_amdgcn_sched_barrier(0);
    __builtin_amdgcn_s_barrier();

    stage(t + 2, cs);
    __builtin_amdgcn_sched_barrier(0);
    __builtin_amdgcn_s_setprio(1);
    #pragma unroll
    for (int ni = 0; ni < 4; ++ni)
      #pragma unroll
      for (int mi = 0; mi < 2; ++mi)
        acc[mi][ni] = __builtin_amdgcn_mfma_f32_16x16x32_bf16(af[mi][1], bfr[ni][1], acc[mi][ni], 0, 0, 0);
    __builtin_amdgcn_s_setprio(0);
    __builtin_amdgcn_sched_barrier(0);
  }
  asm volatile("s_waitcnt vmcnt(0)" ::: "memory");

  #pragma unroll
  for (int mi = 0; mi < 2; ++mi) {
    const int grow = bm * 64 + wr * 32 + mi * 16 + lg * 4;
    #pragma unroll
    for (int ni = 0; ni < 4; ++ni) {
      const int gcol = bn * 128 + wc * 64 + ni * 16 + l15;
      #pragma unroll
      for (int r = 0; r < 4; ++r)
        of[(size_t)(grow + r) * Nout + gcol] += acc[mi][ni][r] + bias[gcol];
    }
  }
}

// ---------------- legacy head GEMM (f32 B, used only if d_ws too small) ----------------
__global__ __launch_bounds__(256) void k_gemm_legacy3(
    const u16* __restrict__ A, const float* __restrict__ B0,
    const float* __restrict__ bias, float* __restrict__ of,
    int M, int N, int K) {
  __shared__ u16 Al[128 * 32];
  __shared__ u16 Bl[32 * 128];
  const int tid = threadIdx.x;
  const int lane = tid & 63;
  const int wid = tid >> 6;
  const int bn = blockIdx.x;
  const int bm = blockIdx.y;
  const int wr = wid >> 1, wc = wid & 1;
  const int l15 = lane & 15, lg = lane >> 4;
  f32x4 acc[4][4];
  #pragma unroll
  for (int i = 0; i < 4; ++i)
    #pragma unroll
    for (int j = 0; j < 4; ++j) { f32x4 z = {0.f,0.f,0.f,0.f}; acc[i][j] = z; }
  const u16* Abase = A + (size_t)(bm * 128) * K;
  const int ar0 = tid >> 2;
  const int ac0 = (tid & 3) * 8;
  const int brow = tid >> 3;
  const int bc0 = (tid & 7) * 16;
  for (int kt = 0; kt < K; kt += 32) {
    *(u16x8*)(Al + ar0 * 32 + ac0) =
        *(const u16x8*)(Abase + (size_t)ar0 * K + kt + ac0);
    *(u16x8*)(Al + (ar0 + 64) * 32 + ac0) =
        *(const u16x8*)(Abase + (size_t)(ar0 + 64) * K + kt + ac0);
    {
      const float* bsrc = B0 + (size_t)(kt + brow) * N + bn * 128 + bc0;
      alignas(16) u16 tmp[16];
      const int colbase = bn * 128 + bc0;
      #pragma unroll
      for (int q = 0; q < 16; ++q)
        tmp[q] = f2bf((colbase + q < N) ? bsrc[q] : 0.0f);
      *(u16x8*)(Bl + brow * 128 + bc0) = *(const u16x8*)tmp;
      *(u16x8*)(Bl + brow * 128 + bc0 + 8) = *(const u16x8*)(tmp + 8);
    }
    __syncthreads();
    bf16x8 af[4];
    #pragma unroll
    for (int mi = 0; mi < 4; ++mi)
      af[mi] = *(const bf16x8*)(Al + (wr * 64 + mi * 16 + l15) * 32 + lg * 8);
    #pragma unroll
    for (int ni = 0; ni < 4; ++ni) {
      u16x8 tv;
      #pragma unroll
      for (int i = 0; i < 8; ++i)
        tv[i] = Bl[(lg * 8 + i) * 128 + wc * 64 + ni * 16 + l15];
      const bf16x8 bfr = __builtin_bit_cast(bf16x8, tv);
      #pragma unroll
      for (int mi = 0; mi < 4; ++mi)
        acc[mi][ni] = __builtin_amdgcn_mfma_f32_16x16x32_bf16(af[mi], bfr, acc[mi][ni], 0, 0, 0);
    }
    __syncthreads();
  }
  #pragma unroll
  for (int mi = 0; mi < 4; ++mi) {
    const int grow = bm * 128 + wr * 64 + mi * 16 + lg * 4;
    #pragma unroll
    for (int ni = 0; ni < 4; ++ni) {
      const int gcol = bn * 128 + wc * 64 + ni * 16 + l15;
      #pragma unroll
      for (int r = 0; r < 4; ++r)
        if (gcol < N) of[(size_t)(grow + r) * N + gcol] = acc[mi][ni][r] + bias[gcol];
    }
  }
}

// ---------------- causal flash attention (XOR-swizzled LDS) ----------------
__global__ __launch_bounds__(256, 2) void k_attn(
    const u16* __restrict__ qg, const u16* __restrict__ kg,
    const u16* __restrict__ vg, u16* __restrict__ og) {
  __shared__ u16 Kl[64 * 64];
  __shared__ u16 Vt[64 * 64];
  __shared__ u16 Pl[4][16 * 64];
  const int tid = threadIdx.x;
  const int lane = tid & 63;
  const int w = tid >> 6;
  const int qt = blockIdx.x;
  const int bh = blockIdx.y;
  const int b = bh >> 4, h = bh & 15;
  const int l15 = lane & 15, lg = lane >> 4;
  char* KlB = (char*)Kl;
  char* VtB = (char*)Vt;
  char* PlB = (char*)(Pl[w]);

  const size_t qrow0 = (size_t)b * cT + qt * 64 + w * 16;
  bf16x8 aq[2];
  #pragma unroll
  for (int c = 0; c < 2; ++c)
    aq[c] = *(const bf16x8*)(qg + (qrow0 + l15) * cE + h * 64 + c * 32 + lg * 8);

  f32x4 acco[4];
  #pragma unroll
  for (int j = 0; j < 4; ++j) { f32x4 z = {0.f,0.f,0.f,0.f}; acco[j] = z; }
  float mrun[4], lrun[4];
  #pragma unroll
  for (int r = 0; r < 4; ++r) { mrun[r] = -1e30f; lrun[r] = 0.f; }

  for (int kt = 0; kt <= qt; ++kt) {
    const size_t krow0 = (size_t)b * cT + kt * 64;
    #pragma unroll
    for (int u = 0; u < 2; ++u) {
      const int un = tid + u * 256;
      const int rr = un >> 3, c8 = (un & 7) * 8;
      *(u16x8*)(KlB + rr * 128 + swzoff(rr, c8 >> 3)) =
          *(const u16x8*)(kg + (krow0 + rr) * cE + h * 64 + c8);
      const u16x8 vv = *(const u16x8*)(vg + (krow0 + rr) * cE + h * 64 + c8);
      #pragma unroll
      for (int i = 0; i < 8; ++i)
        *(u16*)(VtB + (c8 + i) * 128 + swzoff(c8 + i, rr >> 3) + (rr & 7) * 2) = vv[i];
    }
    __syncthreads();

    f32x4 s[4];
    #pragma unroll
    for (int j = 0; j < 4; ++j) { f32x4 z = {0.f,0.f,0.f,0.f}; s[j] = z; }
    #pragma unroll
    for (int c = 0; c < 2; ++c) {
      #pragma unroll
      for (int j = 0; j < 4; ++j) {
        const int n = j * 16 + l15;
        const bf16x8 kb2 = *(const bf16x8*)(KlB + n * 128 + swzoff(n, c * 4 + lg));
        s[j] = __builtin_amdgcn_mfma_f32_16x16x32_bf16(aq[c], kb2, s[j], 0, 0, 0);
      }
    }

    float sv[4][4];
    const bool diag = (kt == qt);
    #pragma unroll
    for (int j = 0; j < 4; ++j)
      #pragma unroll
      for (int r = 0; r < 4; ++r) {
        float xs = s[j][r] * 0.125f;
        if (diag && (j * 16 + l15) > (w * 16 + lg * 4 + r)) xs = -1e30f;
        sv[j][r] = xs;
      }

    float corr[4];
    #pragma unroll
    for (int r = 0; r < 4; ++r) {
      float mx = fmaxf(fmaxf(sv[0][r], sv[1][r]), fmaxf(sv[2][r], sv[3][r]));
      #pragma unroll
      for (int off = 1; off < 16; off <<= 1) mx = fmaxf(mx, __shfl_xor(mx, off));
      const float mnew = fmaxf(mrun[r], mx);
      corr[r] = __expf(mrun[r] - mnew);
      float rs = 0.f;
      #pragma unroll
      for (int j = 0; j < 4; ++j) {
        const float p = __expf(sv[j][r] - mnew);
        sv[j][r] = p;
        rs += p;
      }
      #pragma unroll
      for (int off = 1; off < 16; off <<= 1) rs += __shfl_xor(rs, off);
      lrun[r] = lrun[r] * corr[r] + rs;
      mrun[r] = mnew;
    }

    #pragma unroll
    for (int j = 0; j < 4; ++j)
      #pragma unroll
      for (int r = 0; r < 4; ++r) {
        const int qr = lg * 4 + r, kc = j * 16 + l15;
        *(u16*)(PlB + qr * 128 + swzoff(qr, kc >> 3) + (kc & 7) * 2) = f2bf(sv[j][r]);
        acco[j][r] *= corr[r];
      }

    #pragma unroll
    for (int c = 0; c < 2; ++c) {
      const bf16x8 pa = *(const bf16x8*)(PlB + l15 * 128 + swzoff(l15, c * 4 + lg));
      #pragma unroll
      for (int j = 0; j < 4; ++j) {
        const int n = j * 16 + l15;
        const bf16x8 vb2 = *(const bf16x8*)(VtB + n * 128 + swzoff(n, c * 4 + lg));
        acco[j] = __builtin_amdgcn_mfma_f32_16x16x32_bf16(pa, vb2, acco[j], 0, 0, 0);
      }
    }
    __syncthreads();
  }

  #pragma unroll
  for (int j = 0; j < 4; ++j)
    #pragma unroll
    for (int r = 0; r < 4; ++r)
      og[(qrow0 + lg * 4 + r) * cE + h * 64 + j * 16 + l15] = f2bf(acco[j][r] / lrun[r]);
}

// ---------------- NLL from per-tile partials ----------------
__global__ __launch_bounds__(256) void k_nll2(const float* __restrict__ pm,
    const float* __restrict__ ps, const float* __restrict__ logits,
    const int* __restrict__ tgt, float* __restrict__ nll, int NT) {
  const int row = blockIdx.x * 4 + (threadIdx.x >> 6);
  const int lane = threadIdx.x & 63;
  float m = -1e30f, s = 0.f;
  for (int i = lane; i < NT; i += 64) {
    const float m2 = pm[(size_t)row * NT + i];
    const float s2 = ps[(size_t)row * NT + i];
    const float M = fmaxf(m, m2);
    s = s * __expf(m - M) + s2 * __expf(m2 - M);
    m = M;
  }
  #pragma unroll
  for (int off = 1; off < 64; off <<= 1) {
    const float m2 = __shfl_xor(m, off);
    const float s2 = __shfl_xor(s, off);
    const float M = fmaxf(m, m2);
    s = s * __expf(m - M) + s2 * __expf(m2 - M);
    m = M;
  }
  if (lane == 0)
    nll[row] = logf(s) + m - logits[(size_t)row * cV + tgt[row]];
}

// ---------------- per-row NLL over V (fallback) ----------------
__global__ __launch_bounds__(256) void k_nll(const float* __restrict__ logits,
    const int* __restrict__ tgt, float* __restrict__ nll) {
  const int row = blockIdx.x;
  const float* lp = logits + (size_t)row * cV;
  const int t = threadIdx.x;
  __shared__ float red[8];
  const int wid = t >> 6, lane = t & 63;
  float mx = -1e30f;
  for (int i = t; i < cV; i += 256) mx = fmaxf(mx, lp[i]);
  #pragma unroll
  for (int off = 32; off; off >>= 1) mx = fmaxf(mx, __shfl_xor(mx, off));
  if (lane == 0) red[wid] = mx;
  __syncthreads();
  mx = fmaxf(fmaxf(red[0], red[1]), fmaxf(red[2], red[3]));
  float s = 0.f;
  for (int i = t; i < cV; i += 256) s += __expf(lp[i] - mx);
  #pragma unroll
  for (int off = 32; off; off >>= 1) s += __shfl_xor(s, off);
  if (lane == 0) red[4 + wid] = s;
  __syncthreads();
  if (t == 0) {
    s = red[4] + red[5] + red[6] + red[7];
    nll[row] = logf(s) + mx - lp[tgt[row]];
  }
}

__global__ __launch_bounds__(256) void k_loss(const float* __restrict__ nll,
    float* __restrict__ out) {
  const int t = threadIdx.x;
  float s = 0.f;
  for (int i = t; i < cBT; i += 256) s += nll[i];
  #pragma unroll
  for (int off = 32; off; off >>= 1) s += __shfl_xor(s, off);
  __shared__ float red[4];
  if ((t & 63) == 0) red[t >> 6] = s;
  __syncthreads();
  if (t == 0) out[0] = (red[0] + red[1] + red[2] + red[3]) * (1.0f / cBT);
}

extern "C" void kernel_launch(void* const* d_in, const int* in_sizes, int n_in,
                              void* d_out, int out_size, void* d_ws, size_t ws_size,
                              hipStream_t stream) {
  const int*   idx  = (const int*)d_in[0];
  const int*   tgt  = (const int*)d_in[1];
  const float* tok  = (const float*)d_in[2];
  const float* pos  = (const float*)d_in[3];
  const float* Wq   = (const float*)d_in[4];
  const float* Wk   = (const float*)d_in[5];
  const float* Wv   = (const float*)d_in[6];
  const float* Wo   = (const float*)d_in[7];
  const float* bo   = (const float*)d_in[8];
  const float* ln1g = (const float*)d_in[9];
  const float* ln1b = (const float*)d_in[10];
  const float* ln2g = (const float*)d_in[11];
  const float* ln2b = (const float*)d_in[12];
  const float* W1   = (const float*)d_in[13];
  const float* b1   = (const float*)d_in[14];
  const float* W2   = (const float*)d_in[15];
  const float* b2   = (const float*)d_in[16];
  const float* lnfg = (const float*)d_in[17];
  const float* lnfb = (const float*)d_in[18];
  const float* Wh   = (const float*)d_in[19];
  const float* bh   = (const float*)d_in[20];

  // --- d_out scratch plan (all dead before head GEMM overwrites d_out) ---
  char* ob = (char*)d_out;
  float* x    = (float*)ob;                          // [BT,E] f32, 16 MB
  u16* hb     = (u16*)(ob + (16u << 20));
  u16* qb     = (u16*)(ob + (24u << 20));            // q/k/v contiguous slabs
  u16* kb     = (u16*)(ob + (32u << 20));
  u16* vb     = (u16*)(ob + (40u << 20));
  u16* abuf   = (u16*)(ob + (48u << 20));
  u16* fbuf   = (u16*)(ob + (56u << 20));            // [BT,FF] bf16 -> ends 88M
  u16* W3T    = (u16*)(ob + (128u << 20));           // 12 x [3][E][E] (72MB) -> 200M
  u16* WoT    = (u16*)(ob + (200u << 20));           // 12 x [E][E]   (24MB) -> 224M
  u16* W1T    = (u16*)(ob + (224u << 20));           // 12 x [FF][E]  (96MB) -> 320M
  u16* W2T    = (u16*)(ob + (320u << 20));           // 12 x [E][FF]  (96MB) -> 416M
  // --- d_ws layout ---
  u16* hf     = (u16*)d_ws;                          // 8.39 MB
  float* nll  = (float*)((char*)d_ws + 8388608);
  u16* WheadT = (u16*)((char*)d_ws + 8404992);       // [cVp][E] bf16 (103.3 MB)
  const size_t whead_end = 8404992u + (size_t)cVp * cE * 2u;
  float* pmax = (float*)((char*)d_ws + whead_end);
  float* psum = (float*)((char*)d_ws + whead_end + (size_t)cBT * cNT * 4);
  const size_t ws_need = whead_end + 2u * (size_t)cBT * cNT * 4;
  const bool fast_head = ws_size >= ws_need;

  float* logits = (float*)d_out;
  float* loss = logits + (size_t)cBT * cV;

  const dim3 blk(256);
  const size_t e2 = (size_t)cE * cE, ef = (size_t)cE * cFF;

  // weight conversion (every call)
  k_cvt_t<<<dim3(32, 32, cL), blk, 0, stream>>>(Wq, W3T,          cE, cE, e2, 3 * e2);
  k_cvt_t<<<dim3(32, 32, cL), blk, 0, stream>>>(Wk, W3T + e2,     cE, cE, e2, 3 * e2);
  k_cvt_t<<<dim3(32, 32, cL), blk, 0, stream>>>(Wv, W3T + 2 * e2, cE, cE, e2, 3 * e2);
  k_cvt_t<<<dim3(32, 32, cL), blk, 0, stream>>>(Wo, WoT, cE, cE, e2, e2);
  k_cvt_t<<<dim3(128, 32, cL), blk, 0, stream>>>(W1, W1T, cE, cFF, ef, ef);
  k_cvt_t<<<dim3(32, 128, cL), blk, 0, stream>>>(W2, W2T, cFF, cE, ef, ef);
  if (fast_head)
    k_cvt_t<<<dim3(cVp / 32, 32, 1), blk, 0, stream>>>(Wh, WheadT, cE, cV, 0, 0);

  k_embed<<<dim3(cBT), blk, 0, stream>>>(idx, tok, pos, x);
  for (int l = 0; l < cL; ++l) {
    k_ln<<<dim3(cBT), blk, 0, stream>>>(x, ln1g + l * cE, ln1b + l * cE, hb);
    k_gemm2<0><<<dim3(192), dim3(512), 0, stream>>>(hb, W3T + l * 3 * e2,
        nullptr, qb, nullptr, cE, 3072, 0, 16, nullptr, nullptr);
    k_attn<<<dim3(16, 64), blk, 0, stream>>>(qb, kb, vb, abuf);
    k_gemm_s<<<dim3(512), blk, 0, stream>>>(abuf, WoT + l * e2, bo + l * cE, x, cE, cE, 64);
    k_ln<<<dim3(cBT), blk, 0, stream>>>(x, ln2g + l * cE, ln2b + l * cE, hb);
    k_gemm2<2><<<dim3(256), dim3(512), 0, stream>>>(hb, W1T + l * ef,
        b1 + l * cFF, fbuf, nullptr, cE, cFF, 0, 16, nullptr, nullptr);
    k_gemm_s<<<dim3(512), blk, 0, stream>>>(fbuf, W2T + l * ef, b2 + l * cE, x, cFF, cE, 64);
  }
  k_ln<<<dim3(cBT), blk, 0, stream>>>(x, lnfg, lnfb, hf);
  if (fast_head) {
    k_gemm2<3><<<dim3(16 * cNT), dim3(512), 0, stream>>>(hf, WheadT, bh,
        nullptr, logits, cE, cV, cNT, 16, pmax, psum);
    k_nll2<<<dim3(cBT / 4), blk, 0, stream>>>(pmax, psum, logits, tgt, nll, cNT);
  } else {
    k_gemm_legacy3<<<dim3(393, 32), blk, 0, stream>>>(hf, Wh, bh, logits, cBT, cV, cE);
    k_nll<<<dim3(cBT), blk, 0, stream>>>(logits, tgt, nll);
  }
  k_loss<<<dim3(1), blk, 0, stream>>>(nll, loss);
}

// Round 6
// 4402.489 us; speedup vs baseline: 1.9644x; 1.0591x over previous
//
#include <hip/hip_runtime.h>
#include <cstdint>
#include <cstddef>

typedef unsigned short u16;
typedef __bf16 bf16x8 __attribute__((ext_vector_type(8)));
typedef float f32x4 __attribute__((ext_vector_type(4)));
typedef unsigned short u16x8 __attribute__((ext_vector_type(8)));
typedef unsigned short u16x4 __attribute__((ext_vector_type(4)));

constexpr int cV  = 50257;
constexpr int cVp = 50432;      // padded to 256
constexpr int cNT = cVp / 256;  // 197 head n-tiles
constexpr int cT  = 1024;
constexpr int cE  = 1024;
constexpr int cL  = 12;
constexpr int cFF = 4096;
constexpr int cBT = 4096;       // B*T

__device__ __forceinline__ u16 f2bf(float f) {
  union { float f; unsigned u; } x; x.f = f;
  unsigned r = x.u + 0x7fffu + ((x.u >> 16) & 1u);   // RNE
  return (u16)(r >> 16);
}

// async global->LDS, 16B per lane. dest must be linear in lane order.
__device__ __forceinline__ void gload16(const void* g, void* l) {
  __builtin_amdgcn_global_load_lds(
      (const __attribute__((address_space(1))) void*)g,
      (__attribute__((address_space(3))) void*)l, 16, 0, 0);
}

// XOR swizzle for 128B-wide LDS rows (attn): permute 16B chunks within row.
__device__ __forceinline__ int swzoff(int row, int chunk) {
  return ((chunk ^ (row & 7) ^ ((row >> 3) & 7)) << 4);
}

// bijective XCD-chunk swizzle for grids with nwg % 8 == 0 (k_gemm_s only)
__device__ __forceinline__ int xcd_swz(int id, int nwg) {
  if ((nwg & 7) == 0) { const int q = nwg >> 3; return (id & 7) * q + (id >> 3); }
  return id;
}

// ---------------- embedding ----------------
__global__ __launch_bounds__(256) void k_embed(const int* __restrict__ idx,
    const float* __restrict__ tok, const float* __restrict__ pos,
    float* __restrict__ x) {
  const int row = blockIdx.x;
  const int t = row & (cT - 1);
  const int tk = idx[row];
  const float4* tv = (const float4*)(tok + (size_t)tk * cE);
  const float4* pv = (const float4*)(pos + (size_t)t * cE);
  float4* xv = (float4*)(x + (size_t)row * cE);
  const int i = threadIdx.x;
  float4 a = tv[i];
  float4 p = pv[i];
  a.x += p.x; a.y += p.y; a.z += p.z; a.w += p.w;
  xv[i] = a;
}

// ---------------- layernorm (f32 in -> bf16 out) ----------------
__global__ __launch_bounds__(256) void k_ln(const float* __restrict__ x,
    const float* __restrict__ gw, const float* __restrict__ bw,
    u16* __restrict__ out) {
  const int row = blockIdx.x;
  const int t = threadIdx.x;
  const float4 v = ((const float4*)(x + (size_t)row * cE))[t];
  float s1 = v.x + v.y + v.z + v.w;
  float s2 = v.x * v.x + v.y * v.y + v.z * v.z + v.w * v.w;
  #pragma unroll
  for (int off = 32; off; off >>= 1) {
    s1 += __shfl_xor(s1, off);
    s2 += __shfl_xor(s2, off);
  }
  __shared__ float red[8];
  const int wid = t >> 6;
  if ((t & 63) == 0) { red[wid] = s1; red[4 + wid] = s2; }
  __syncthreads();
  s1 = red[0] + red[1] + red[2] + red[3];
  s2 = red[4] + red[5] + red[6] + red[7];
  const float mean = s1 * (1.0f / cE);
  const float var = s2 * (1.0f / cE) - mean * mean;
  const float rs = rsqrtf(var + 1e-5f);
  const float4 g4 = ((const float4*)gw)[t];
  const float4 b4 = ((const float4*)bw)[t];
  u16x4 o;
  o[0] = f2bf((v.x - mean) * rs * g4.x + b4.x);
  o[1] = f2bf((v.y - mean) * rs * g4.y + b4.y);
  o[2] = f2bf((v.z - mean) * rs * g4.z + b4.z);
  o[3] = f2bf((v.w - mean) * rs * g4.w + b4.w);
  *(u16x4*)(out + (size_t)row * cE + t * 4) = o;
}

// ---------------- weight convert+transpose: f32[K][N] -> bf16[N][K] ----------------
__global__ __launch_bounds__(256) void k_cvt_t(const float* __restrict__ src,
    u16* __restrict__ dst, int K, int Nsrc, size_t sstride, size_t dstride) {
  __shared__ float tile[32][33];
  const float* s = src + blockIdx.z * sstride;
  u16* d = dst + blockIdx.z * dstride;
  const int n0 = blockIdx.x * 32, k0 = blockIdx.y * 32;
  const int t = threadIdx.x;
  const int c = t & 31, r0 = t >> 5;
  #pragma unroll
  for (int i = 0; i < 4; ++i) {
    const int kl = r0 + i * 8;
    const int n = n0 + c;
    tile[kl][c] = (n < Nsrc) ? s[(size_t)(k0 + kl) * Nsrc + n] : 0.0f;
  }
  __syncthreads();
  #pragma unroll
  for (int i = 0; i < 4; ++i) {
    const int nl = r0 + i * 8;
    d[(size_t)(n0 + nl) * K + k0 + c] = f2bf(tile[c][nl]);
  }
}

// ============== 128x256 GEMM, BK=32, 2 blocks/CU (TLP-first) ==============
// C[M,Nout] = A[M][K](bf16) @ Bt[Npad][K](bf16)^T. 512 thr = 8 waves (2M x
// 4N), wave-out 64x64, acc 4x4 (64 VGPR) -> launch_bounds(512,4) keeps regs
// <=128 so TWO blocks co-reside per CU (epilogue/drain overlap via TLP).
// LDS 48KB = 2 dbuf x (A 8KB + B 16KB). Rows 64B = 4 x 16B chunks, chunk
// XOR-swizzled by (row>>1)&3 (quarter-wave-verified 2-way = free); global
// source pre-swizzled (both-sides rule). Loop (T3-minimal): STAGE(t+1)
// issued first, ds_reads, 16 MFMA, vmcnt(0)+barrier once per tile.
// EPI: 0 bf16 qkv slabs | 2 bf16 gelu | 3 f32 head + fused softmax partials
template<int EPI>
__global__ __launch_bounds__(512, 4) void k_gemm2(
    const u16* __restrict__ A, const u16* __restrict__ Bt,
    const float* __restrict__ bias, u16* __restrict__ obf,
    float* __restrict__ of, int K, int Nout, int ntile, int mt,
    float* __restrict__ pm, float* __restrict__ ps) {
  __shared__ __align__(16) char smem[49152];
  const int tid = threadIdx.x;
  const int lane = tid & 63;
  const int wid = tid >> 6;
  const int wg = (int)blockIdx.x;
  const int bm = wg % mt;            // bm-fast: all CUs sweep same B panel
  const int bn = wg / mt;
  const int wm = wid >> 2, wn = wid & 3;
  const int l15 = lane & 15, lg = lane >> 4;

  f32x4 acc[4][4];
  #pragma unroll
  for (int i = 0; i < 4; ++i)
    #pragma unroll
    for (int j = 0; j < 4; ++j) { f32x4 z = {0.f,0.f,0.f,0.f}; acc[i][j] = z; }

  const u16* Ab = A + (size_t)(bm * 128) * K;
  const u16* Bb = Bt + (size_t)(bn * 256) * K;
  const int nt = K >> 5;

  auto stage = [&](int t) {
    char* buf = smem + ((t & 1) ? 24576 : 0);
    const int kt = t << 5;
    {
      const int r = tid >> 2, c = tid & 3;
      gload16(Ab + (size_t)r * K + kt + ((c ^ ((r >> 1) & 3)) << 3),
              buf + tid * 16);
    }
    #pragma unroll
    for (int p = 0; p < 2; ++p) {
      const int L = p * 512 + tid;
      const int r = L >> 2, c = L & 3;
      gload16(Bb + (size_t)r * K + kt + ((c ^ ((r >> 1) & 3)) << 3),
              buf + 8192 + L * 16);
    }
  };

  stage(0);
  asm volatile("s_waitcnt vmcnt(0)" ::: "memory");
  __builtin_amdgcn_s_barrier();

  for (int t = 0; t < nt; ++t) {
    if (t + 1 < nt) stage(t + 1);            // issue-early into other buffer
    char* cs = smem + ((t & 1) ? 24576 : 0);
    const char* csB = cs + 8192;
    bf16x8 af[4], bfr[4];
    #pragma unroll
    for (int mi = 0; mi < 4; ++mi) {
      const int row = wm * 64 + mi * 16 + l15;
      af[mi] = *(const bf16x8*)(cs + row * 64 + ((lg ^ ((row >> 1) & 3)) << 4));
    }
    #pragma unroll
    for (int ni = 0; ni < 4; ++ni) {
      const int row = wn * 64 + ni * 16 + l15;
      bfr[ni] = *(const bf16x8*)(csB + row * 64 + ((lg ^ ((row >> 1) & 3)) << 4));
    }
    __builtin_amdgcn_sched_barrier(0);
    __builtin_amdgcn_s_setprio(1);
    #pragma unroll
    for (int ni = 0; ni < 4; ++ni)
      #pragma unroll
      for (int mi = 0; mi < 4; ++mi)
        acc[mi][ni] = __builtin_amdgcn_mfma_f32_16x16x32_bf16(af[mi], bfr[ni], acc[mi][ni], 0, 0, 0);
    __builtin_amdgcn_s_setprio(0);
    __builtin_amdgcn_sched_barrier(0);
    asm volatile("s_waitcnt vmcnt(0)" ::: "memory");
    __builtin_amdgcn_s_barrier();
  }

  // ---- epilogue ----
  if constexpr (EPI == 3) {
    __syncthreads();                      // repurpose smem
    float* pb = (float*)smem;             // [128][4][2]
    #pragma unroll
    for (int mi = 0; mi < 4; ++mi) {
      const int grow = bm * 128 + wm * 64 + mi * 16 + lg * 4;
      float rm[4];
      #pragma unroll
      for (int r = 0; r < 4; ++r) rm[r] = -1e30f;
      #pragma unroll
      for (int ni = 0; ni < 4; ++ni) {
        const int gcol = bn * 256 + wn * 64 + ni * 16 + l15;
        const bool ok = gcol < Nout;
        const float bb = ok ? bias[gcol] : 0.0f;
        #pragma unroll
        for (int r = 0; r < 4; ++r) {
          const float v = ok ? (acc[mi][ni][r] + bb) : -1e30f;
          acc[mi][ni][r] = v;
          if (ok) of[(size_t)(grow + r) * Nout + gcol] = v;
          rm[r] = fmaxf(rm[r], v);
        }
      }
      #pragma unroll
      for (int r = 0; r < 4; ++r) {
        float m = rm[r];
        #pragma unroll
        for (int off = 1; off < 16; off <<= 1) m = fmaxf(m, __shfl_xor(m, off));
        float s = 0.f;
        #pragma unroll
        for (int ni = 0; ni < 4; ++ni) s += __expf(acc[mi][ni][r] - m);
        #pragma unroll
        for (int off = 1; off < 16; off <<= 1) s += __shfl_xor(s, off);
        if (l15 == 0) {
          const int lrow = wm * 64 + mi * 16 + lg * 4 + r;
          pb[(lrow * 4 + wn) * 2] = m;
          pb[(lrow * 4 + wn) * 2 + 1] = s;
        }
      }
    }
    __syncthreads();
    if (tid < 128) {
      float m = -1e30f, s = 0.f;
      #pragma unroll
      for (int q = 0; q < 4; ++q) {
        const float m2 = pb[(tid * 4 + q) * 2];
        const float s2 = pb[(tid * 4 + q) * 2 + 1];
        const float M = fmaxf(m, m2);
        s = s * __expf(m - M) + s2 * __expf(m2 - M);
        m = M;
      }
      const size_t grow = (size_t)(bm * 128 + tid);
      pm[grow * ntile + bn] = m;
      ps[grow * ntile + bn] = s;
    }
  } else {
    #pragma unroll
    for (int mi = 0; mi < 4; ++mi) {
      const int grow = bm * 128 + wm * 64 + mi * 16 + lg * 4;
      #pragma unroll
      for (int ni = 0; ni < 4; ++ni) {
        const int gcol = bn * 256 + wn * 64 + ni * 16 + l15;
        #pragma unroll
        for (int r = 0; r < 4; ++r) {
          const float a = acc[mi][ni][r];
          if constexpr (EPI == 0) {
            obf[(size_t)(gcol >> 10) * 4194304 + (size_t)(grow + r) * 1024 + (gcol & 1023)] = f2bf(a);
          } else {
            const float gv = a + bias[gcol];
            obf[(size_t)(grow + r) * Nout + gcol] = f2bf(0.5f * gv * (1.0f + erff(gv * 0.70710678118f)));
          }
        }
      }
    }
  }
}

// ------- small-M pipelined GEMM: 64x128 tile, BK=64, residual += -------
__global__ __launch_bounds__(256) void k_gemm_s(
    const u16* __restrict__ A, const u16* __restrict__ Bt,
    const float* __restrict__ bias, float* __restrict__ of,
    int K, int Nout, int mt) {
  __shared__ __align__(16) char smem[49152];
  const int tid = threadIdx.x;
  const int lane = tid & 63;
  const int wid = tid >> 6;
  const int wg = xcd_swz((int)blockIdx.x, (int)gridDim.x);
  const int bm = wg % mt;
  const int bn = wg / mt;
  const int wr = wid >> 1, wc = wid & 1;
  const int l15 = lane & 15, lg = lane >> 4;

  f32x4 acc[2][4];
  #pragma unroll
  for (int i = 0; i < 2; ++i)
    #pragma unroll
    for (int j = 0; j < 4; ++j) { f32x4 z = {0.f,0.f,0.f,0.f}; acc[i][j] = z; }

  const u16* Ab = A + (size_t)(bm * 64) * K;
  const u16* Bb = Bt + (size_t)(bn * 128) * K;
  const int nt = K >> 6;

  auto stage = [&](int t, char* buf) {
    const int kt = (t < nt ? t : nt - 1) << 6;
    #pragma unroll
    for (int p = 0; p < 2; ++p) {
      const int L = p * 256 + tid;
      const int row = L >> 3, cc = L & 7;
      gload16(Ab + (size_t)row * K + kt + ((cc ^ (row & 7)) << 3), buf + L * 16);
    }
    #pragma unroll
    for (int p = 0; p < 4; ++p) {
      const int L = p * 256 + tid;
      const int row = L >> 3, cc = L & 7;
      gload16(Bb + (size_t)row * K + kt + ((cc ^ (row & 7)) << 3), buf + 8192 + L * 16);
    }
  };
  stage(0, smem);
  stage(1, smem + 24576);

  for (int t = 0; t < nt; ++t) {
    char* cs = smem + ((t & 1) ? 24576 : 0);
    const char* csB = cs + 8192;
    asm volatile("s_waitcnt vmcnt(6)" ::: "memory");
    __builtin_amdgcn_s_barrier();

    bf16x8 af[2][2], bfr[4][2];
    #pragma unroll
    for (int mi = 0; mi < 2; ++mi) {
      const int row = wr * 32 + mi * 16 + l15;
      #pragma unroll
      for (int kk = 0; kk < 2; ++kk)
        af[mi][kk] = *(const bf16x8*)(cs + row * 128 + (((kk * 4 + lg) ^ (row & 7)) << 4));
    }
    #pragma unroll
    for (int ni = 0; ni < 4; ++ni) {
      const int row = wc * 64 + ni * 16 + l15;
      #pragma unroll
      for (int kk = 0; kk < 2; ++kk)
        bfr[ni][kk] = *(const bf16x8*)(csB + row * 128 + (((kk * 4 + lg) ^ (row & 7)) << 4));
    }
    __builtin_amdgcn_sched_barrier(0);
    __builtin_amdgcn_s_setprio(1);
    #pragma unroll
    for (int ni = 0; ni < 4; ++ni)
      #pragma unroll
      for (int mi = 0; mi < 2; ++mi)
        acc[mi][ni] = __builtin_amdgcn_mfma_f32_16x16x32_bf16(af[mi][0], bfr[ni][0], acc[mi][ni], 0, 0, 0);
    __builtin_amdgcn_s_setprio(0);
    __builtin_amdgcn_sched_barrier(0);
    asm volatile("s_waitcnt lgkmcnt(0)" ::: "memory");
    __builtin_amdgcn_sched_barrier(0);
    __builtin_amdgcn_s_barrier();

    stage(t + 2, cs);
    __builtin_amdgcn_sched_barrier(0);
    __builtin_amdgcn_s_setprio(1);
    #pragma unroll
    for (int ni = 0; ni < 4; ++ni)
      #pragma unroll
      for (int mi = 0; mi < 2; ++mi)
        acc[mi][ni] = __builtin_amdgcn_mfma_f32_16x16x32_bf16(af[mi][1], bfr[ni][1], acc[mi][ni], 0, 0, 0);
    __builtin_amdgcn_s_setprio(0);
    __builtin_amdgcn_sched_barrier(0);
  }
  asm volatile("s_waitcnt vmcnt(0)" ::: "memory");

  #pragma unroll
  for (int mi = 0; mi < 2; ++mi) {
    const int grow = bm * 64 + wr * 32 + mi * 16 + lg * 4;
    #pragma unroll
    for (int ni = 0; ni < 4; ++ni) {
      const int gcol = bn * 128 + wc * 64 + ni * 16 + l15;
      #pragma unroll
      for (int r = 0; r < 4; ++r)
        of[(size_t)(grow + r) * Nout + gcol] += acc[mi][ni][r] + bias[gcol];
    }
  }
}

// ---------------- legacy head GEMM (f32 B, used only if d_ws too small) ----------------
__global__ __launch_bounds__(256) void k_gemm_legacy3(
    const u16* __restrict__ A, const float* __restrict__ B0,
    const float* __restrict__ bias, float* __restrict__ of,
    int M, int N, int K) {
  __shared__ u16 Al[128 * 32];
  __shared__ u16 Bl[32 * 128];
  const int tid = threadIdx.x;
  const int lane = tid & 63;
  const int wid = tid >> 6;
  const int bn = blockIdx.x;
  const int bm = blockIdx.y;
  const int wr = wid >> 1, wc = wid & 1;
  const int l15 = lane & 15, lg = lane >> 4;
  f32x4 acc[4][4];
  #pragma unroll
  for (int i = 0; i < 4; ++i)
    #pragma unroll
    for (int j = 0; j < 4; ++j) { f32x4 z = {0.f,0.f,0.f,0.f}; acc[i][j] = z; }
  const u16* Abase = A + (size_t)(bm * 128) * K;
  const int ar0 = tid >> 2;
  const int ac0 = (tid & 3) * 8;
  const int brow = tid >> 3;
  const int bc0 = (tid & 7) * 16;
  for (int kt = 0; kt < K; kt += 32) {
    *(u16x8*)(Al + ar0 * 32 + ac0) =
        *(const u16x8*)(Abase + (size_t)ar0 * K + kt + ac0);
    *(u16x8*)(Al + (ar0 + 64) * 32 + ac0) =
        *(const u16x8*)(Abase + (size_t)(ar0 + 64) * K + kt + ac0);
    {
      const float* bsrc = B0 + (size_t)(kt + brow) * N + bn * 128 + bc0;
      alignas(16) u16 tmp[16];
      const int colbase = bn * 128 + bc0;
      #pragma unroll
      for (int q = 0; q < 16; ++q)
        tmp[q] = f2bf((colbase + q < N) ? bsrc[q] : 0.0f);
      *(u16x8*)(Bl + brow * 128 + bc0) = *(const u16x8*)tmp;
      *(u16x8*)(Bl + brow * 128 + bc0 + 8) = *(const u16x8*)(tmp + 8);
    }
    __syncthreads();
    bf16x8 af[4];
    #pragma unroll
    for (int mi = 0; mi < 4; ++mi)
      af[mi] = *(const bf16x8*)(Al + (wr * 64 + mi * 16 + l15) * 32 + lg * 8);
    #pragma unroll
    for (int ni = 0; ni < 4; ++ni) {
      u16x8 tv;
      #pragma unroll
      for (int i = 0; i < 8; ++i)
        tv[i] = Bl[(lg * 8 + i) * 128 + wc * 64 + ni * 16 + l15];
      const bf16x8 bfr = __builtin_bit_cast(bf16x8, tv);
      #pragma unroll
      for (int mi = 0; mi < 4; ++mi)
        acc[mi][ni] = __builtin_amdgcn_mfma_f32_16x16x32_bf16(af[mi], bfr, acc[mi][ni], 0, 0, 0);
    }
    __syncthreads();
  }
  #pragma unroll
  for (int mi = 0; mi < 4; ++mi) {
    const int grow = bm * 128 + wr * 64 + mi * 16 + lg * 4;
    #pragma unroll
    for (int ni = 0; ni < 4; ++ni) {
      const int gcol = bn * 128 + wc * 64 + ni * 16 + l15;
      #pragma unroll
      for (int r = 0; r < 4; ++r)
        if (gcol < N) of[(size_t)(grow + r) * N + gcol] = acc[mi][ni][r] + bias[gcol];
    }
  }
}

// ---------------- causal flash attention (XOR-swizzled LDS) ----------------
__global__ __launch_bounds__(256, 2) void k_attn(
    const u16* __restrict__ qg, const u16* __restrict__ kg,
    const u16* __restrict__ vg, u16* __restrict__ og) {
  __shared__ u16 Kl[64 * 64];
  __shared__ u16 Vt[64 * 64];
  __shared__ u16 Pl[4][16 * 64];
  const int tid = threadIdx.x;
  const int lane = tid & 63;
  const int w = tid >> 6;
  const int qt = blockIdx.x;
  const int bh = blockIdx.y;
  const int b = bh >> 4, h = bh & 15;
  const int l15 = lane & 15, lg = lane >> 4;
  char* KlB = (char*)Kl;
  char* VtB = (char*)Vt;
  char* PlB = (char*)(Pl[w]);

  const size_t qrow0 = (size_t)b * cT + qt * 64 + w * 16;
  bf16x8 aq[2];
  #pragma unroll
  for (int c = 0; c < 2; ++c)
    aq[c] = *(const bf16x8*)(qg + (qrow0 + l15) * cE + h * 64 + c * 32 + lg * 8);

  f32x4 acco[4];
  #pragma unroll
  for (int j = 0; j < 4; ++j) { f32x4 z = {0.f,0.f,0.f,0.f}; acco[j] = z; }
  float mrun[4], lrun[4];
  #pragma unroll
  for (int r = 0; r < 4; ++r) { mrun[r] = -1e30f; lrun[r] = 0.f; }

  for (int kt = 0; kt <= qt; ++kt) {
    const size_t krow0 = (size_t)b * cT + kt * 64;
    #pragma unroll
    for (int u = 0; u < 2; ++u) {
      const int un = tid + u * 256;
      const int rr = un >> 3, c8 = (un & 7) * 8;
      *(u16x8*)(KlB + rr * 128 + swzoff(rr, c8 >> 3)) =
          *(const u16x8*)(kg + (krow0 + rr) * cE + h * 64 + c8);
      const u16x8 vv = *(const u16x8*)(vg + (krow0 + rr) * cE + h * 64 + c8);
      #pragma unroll
      for (int i = 0; i < 8; ++i)
        *(u16*)(VtB + (c8 + i) * 128 + swzoff(c8 + i, rr >> 3) + (rr & 7) * 2) = vv[i];
    }
    __syncthreads();

    f32x4 s[4];
    #pragma unroll
    for (int j = 0; j < 4; ++j) { f32x4 z = {0.f,0.f,0.f,0.f}; s[j] = z; }
    #pragma unroll
    for (int c = 0; c < 2; ++c) {
      #pragma unroll
      for (int j = 0; j < 4; ++j) {
        const int n = j * 16 + l15;
        const bf16x8 kb2 = *(const bf16x8*)(KlB + n * 128 + swzoff(n, c * 4 + lg));
        s[j] = __builtin_amdgcn_mfma_f32_16x16x32_bf16(aq[c], kb2, s[j], 0, 0, 0);
      }
    }

    float sv[4][4];
    const bool diag = (kt == qt);
    #pragma unroll
    for (int j = 0; j < 4; ++j)
      #pragma unroll
      for (int r = 0; r < 4; ++r) {
        float xs = s[j][r] * 0.125f;
        if (diag && (j * 16 + l15) > (w * 16 + lg * 4 + r)) xs = -1e30f;
        sv[j][r] = xs;
      }

    float corr[4];
    #pragma unroll
    for (int r = 0; r < 4; ++r) {
      float mx = fmaxf(fmaxf(sv[0][r], sv[1][r]), fmaxf(sv[2][r], sv[3][r]));
      #pragma unroll
      for (int off = 1; off < 16; off <<= 1) mx = fmaxf(mx, __shfl_xor(mx, off));
      const float mnew = fmaxf(mrun[r], mx);
      corr[r] = __expf(mrun[r] - mnew);
      float rs = 0.f;
      #pragma unroll
      for (int j = 0; j < 4; ++j) {
        const float p = __expf(sv[j][r] - mnew);
        sv[j][r] = p;
        rs += p;
      }
      #pragma unroll
      for (int off = 1; off < 16; off <<= 1) rs += __shfl_xor(rs, off);
      lrun[r] = lrun[r] * corr[r] + rs;
      mrun[r] = mnew;
    }

    #pragma unroll
    for (int j = 0; j < 4; ++j)
      #pragma unroll
      for (int r = 0; r < 4; ++r) {
        const int qr = lg * 4 + r, kc = j * 16 + l15;
        *(u16*)(PlB + qr * 128 + swzoff(qr, kc >> 3) + (kc & 7) * 2) = f2bf(sv[j][r]);
        acco[j][r] *= corr[r];
      }

    #pragma unroll
    for (int c = 0; c < 2; ++c) {
      const bf16x8 pa = *(const bf16x8*)(PlB + l15 * 128 + swzoff(l15, c * 4 + lg));
      #pragma unroll
      for (int j = 0; j < 4; ++j) {
        const int n = j * 16 + l15;
        const bf16x8 vb2 = *(const bf16x8*)(VtB + n * 128 + swzoff(n, c * 4 + lg));
        acco[j] = __builtin_amdgcn_mfma_f32_16x16x32_bf16(pa, vb2, acco[j], 0, 0, 0);
      }
    }
    __syncthreads();
  }

  #pragma unroll
  for (int j = 0; j < 4; ++j)
    #pragma unroll
    for (int r = 0; r < 4; ++r)
      og[(qrow0 + lg * 4 + r) * cE + h * 64 + j * 16 + l15] = f2bf(acco[j][r] / lrun[r]);
}

// ---------------- NLL from per-tile partials ----------------
__global__ __launch_bounds__(256) void k_nll2(const float* __restrict__ pm,
    const float* __restrict__ ps, const float* __restrict__ logits,
    const int* __restrict__ tgt, float* __restrict__ nll, int NT) {
  const int row = blockIdx.x * 4 + (threadIdx.x >> 6);
  const int lane = threadIdx.x & 63;
  float m = -1e30f, s = 0.f;
  for (int i = lane; i < NT; i += 64) {
    const float m2 = pm[(size_t)row * NT + i];
    const float s2 = ps[(size_t)row * NT + i];
    const float M = fmaxf(m, m2);
    s = s * __expf(m - M) + s2 * __expf(m2 - M);
    m = M;
  }
  #pragma unroll
  for (int off = 1; off < 64; off <<= 1) {
    const float m2 = __shfl_xor(m, off);
    const float s2 = __shfl_xor(s, off);
    const float M = fmaxf(m, m2);
    s = s * __expf(m - M) + s2 * __expf(m2 - M);
    m = M;
  }
  if (lane == 0)
    nll[row] = logf(s) + m - logits[(size_t)row * cV + tgt[row]];
}

// ---------------- per-row NLL over V (fallback) ----------------
__global__ __launch_bounds__(256) void k_nll(const float* __restrict__ logits,
    const int* __restrict__ tgt, float* __restrict__ nll) {
  const int row = blockIdx.x;
  const float* lp = logits + (size_t)row * cV;
  const int t = threadIdx.x;
  __shared__ float red[8];
  const int wid = t >> 6, lane = t & 63;
  float mx = -1e30f;
  for (int i = t; i < cV; i += 256) mx = fmaxf(mx, lp[i]);
  #pragma unroll
  for (int off = 32; off; off >>= 1) mx = fmaxf(mx, __shfl_xor(mx, off));
  if (lane == 0) red[wid] = mx;
  __syncthreads();
  mx = fmaxf(fmaxf(red[0], red[1]), fmaxf(red[2], red[3]));
  float s = 0.f;
  for (int i = t; i < cV; i += 256) s += __expf(lp[i] - mx);
  #pragma unroll
  for (int off = 32; off; off >>= 1) s += __shfl_xor(s, off);
  if (lane == 0) red[4 + wid] = s;
  __syncthreads();
  if (t == 0) {
    s = red[4] + red[5] + red[6] + red[7];
    nll[row] = logf(s) + mx - lp[tgt[row]];
  }
}

__global__ __launch_bounds__(256) void k_loss(const float* __restrict__ nll,
    float* __restrict__ out) {
  const int t = threadIdx.x;
  float s = 0.f;
  for (int i = t; i < cBT; i += 256) s += nll[i];
  #pragma unroll
  for (int off = 32; off; off >>= 1) s += __shfl_xor(s, off);
  __shared__ float red[4];
  if ((t & 63) == 0) red[t >> 6] = s;
  __syncthreads();
  if (t == 0) out[0] = (red[0] + red[1] + red[2] + red[3]) * (1.0f / cBT);
}

extern "C" void kernel_launch(void* const* d_in, const int* in_sizes, int n_in,
                              void* d_out, int out_size, void* d_ws, size_t ws_size,
                              hipStream_t stream) {
  const int*   idx  = (const int*)d_in[0];
  const int*   tgt  = (const int*)d_in[1];
  const float* tok  = (const float*)d_in[2];
  const float* pos  = (const float*)d_in[3];
  const float* Wq   = (const float*)d_in[4];
  const float* Wk   = (const float*)d_in[5];
  const float* Wv   = (const float*)d_in[6];
  const float* Wo   = (const float*)d_in[7];
  const float* bo   = (const float*)d_in[8];
  const float* ln1g = (const float*)d_in[9];
  const float* ln1b = (const float*)d_in[10];
  const float* ln2g = (const float*)d_in[11];
  const float* ln2b = (const float*)d_in[12];
  const float* W1   = (const float*)d_in[13];
  const float* b1   = (const float*)d_in[14];
  const float* W2   = (const float*)d_in[15];
  const float* b2   = (const float*)d_in[16];
  const float* lnfg = (const float*)d_in[17];
  const float* lnfb = (const float*)d_in[18];
  const float* Wh   = (const float*)d_in[19];
  const float* bh   = (const float*)d_in[20];

  // --- d_out scratch plan (all dead before head GEMM overwrites d_out) ---
  char* ob = (char*)d_out;
  float* x    = (float*)ob;                          // [BT,E] f32, 16 MB
  u16* hb     = (u16*)(ob + (16u << 20));
  u16* qb     = (u16*)(ob + (24u << 20));            // q/k/v contiguous slabs
  u16* kb     = (u16*)(ob + (32u << 20));
  u16* vb     = (u16*)(ob + (40u << 20));
  u16* abuf   = (u16*)(ob + (48u << 20));
  u16* fbuf   = (u16*)(ob + (56u << 20));            // [BT,FF] bf16 -> ends 88M
  u16* W3T    = (u16*)(ob + (128u << 20));           // 12 x [3][E][E] (72MB) -> 200M
  u16* WoT    = (u16*)(ob + (200u << 20));           // 12 x [E][E]   (24MB) -> 224M
  u16* W1T    = (u16*)(ob + (224u << 20));           // 12 x [FF][E]  (96MB) -> 320M
  u16* W2T    = (u16*)(ob + (320u << 20));           // 12 x [E][FF]  (96MB) -> 416M
  // --- d_ws layout ---
  u16* hf     = (u16*)d_ws;                          // 8.39 MB
  float* nll  = (float*)((char*)d_ws + 8388608);
  u16* WheadT = (u16*)((char*)d_ws + 8404992);       // [cVp][E] bf16 (103.3 MB)
  const size_t whead_end = 8404992u + (size_t)cVp * cE * 2u;
  float* pmax = (float*)((char*)d_ws + whead_end);
  float* psum = (float*)((char*)d_ws + whead_end + (size_t)cBT * cNT * 4);
  const size_t ws_need = whead_end + 2u * (size_t)cBT * cNT * 4;
  const bool fast_head = ws_size >= ws_need;

  float* logits = (float*)d_out;
  float* loss = logits + (size_t)cBT * cV;

  const dim3 blk(256);
  const size_t e2 = (size_t)cE * cE, ef = (size_t)cE * cFF;

  // weight conversion (every call)
  k_cvt_t<<<dim3(32, 32, cL), blk, 0, stream>>>(Wq, W3T,          cE, cE, e2, 3 * e2);
  k_cvt_t<<<dim3(32, 32, cL), blk, 0, stream>>>(Wk, W3T + e2,     cE, cE, e2, 3 * e2);
  k_cvt_t<<<dim3(32, 32, cL), blk, 0, stream>>>(Wv, W3T + 2 * e2, cE, cE, e2, 3 * e2);
  k_cvt_t<<<dim3(32, 32, cL), blk, 0, stream>>>(Wo, WoT, cE, cE, e2, e2);
  k_cvt_t<<<dim3(128, 32, cL), blk, 0, stream>>>(W1, W1T, cE, cFF, ef, ef);
  k_cvt_t<<<dim3(32, 128, cL), blk, 0, stream>>>(W2, W2T, cFF, cE, ef, ef);
  if (fast_head)
    k_cvt_t<<<dim3(cVp / 32, 32, 1), blk, 0, stream>>>(Wh, WheadT, cE, cV, 0, 0);

  k_embed<<<dim3(cBT), blk, 0, stream>>>(idx, tok, pos, x);
  for (int l = 0; l < cL; ++l) {
    k_ln<<<dim3(cBT), blk, 0, stream>>>(x, ln1g + l * cE, ln1b + l * cE, hb);
    k_gemm2<0><<<dim3(32 * 12), dim3(512), 0, stream>>>(hb, W3T + l * 3 * e2,
        nullptr, qb, nullptr, cE, 3072, 0, 32, nullptr, nullptr);
    k_attn<<<dim3(16, 64), blk, 0, stream>>>(qb, kb, vb, abuf);
    k_gemm_s<<<dim3(512), blk, 0, stream>>>(abuf, WoT + l * e2, bo + l * cE, x, cE, cE, 64);
    k_ln<<<dim3(cBT), blk, 0, stream>>>(x, ln2g + l * cE, ln2b + l * cE, hb);
    k_gemm2<2><<<dim3(32 * 16), dim3(512), 0, stream>>>(hb, W1T + l * ef,
        b1 + l * cFF, fbuf, nullptr, cE, cFF, 0, 32, nullptr, nullptr);
    k_gemm_s<<<dim3(512), blk, 0, stream>>>(fbuf, W2T + l * ef, b2 + l * cE, x, cFF, cE, 64);
  }
  k_ln<<<dim3(cBT), blk, 0, stream>>>(x, lnfg, lnfb, hf);
  if (fast_head) {
    k_gemm2<3><<<dim3(32 * cNT), dim3(512), 0, stream>>>(hf, WheadT, bh,
        nullptr, logits, cE, cV, cNT, 32, pmax, psum);
    k_nll2<<<dim3(cBT / 4), blk, 0, stream>>>(pmax, psum, logits, tgt, nll, cNT);
  } else {
    k_gemm_legacy3<<<dim3(393, 32), blk, 0, stream>>>(hf, Wh, bh, logits, cBT, cV, cE);
    k_nll<<<dim3(cBT), blk, 0, stream>>>(logits, tgt, nll);
  }
  k_loss<<<dim3(1), blk, 0, stream>>>(nll, loss);
}